// Round 1
// baseline (7266.135 us; speedup 1.0000x reference)
//
#include <hip/hip_runtime.h>

#define BB 512
#define TT 128
#define VV 64
#define EE 256
#define HH 512
#define LL 128

typedef __bf16 bf16x8 __attribute__((ext_vector_type(8)));
typedef float f32x4 __attribute__((ext_vector_type(4)));
typedef unsigned short u16;

#define PITCH_E 792   // 768+24 elems, 1584B: 16B aligned, ~2-way banks
#define PITCH_D 920   // 896+24
#define PITCH_R 536   // 512+24

// ---- workspace layout (bytes) ----
#define ENC_TOT  3145728   // enc weight frag elems (2 dirs x 768x2048)
#define DEC_TOT  1835008   // dec weight frag elems (896x2048)
#define WOUT_TOT 32768     // W_out frag elems (512x64)
#define OFF_ENCW 0ull
#define OFF_DECW 6291456ull
#define OFF_WOUT 9961472ull
#define OFF_HENC 10027008ull   // [2dir][2buf][512][512] bf16
#define OFF_HDEC 12124160ull   // [2buf][512][512] bf16
#define OFF_ZBF  13172736ull   // [512][128] bf16
#define OFF_HS   13303808ull   // [128][512][512] bf16
#define OFF_BAR  80412672ull   // 4 uints (enc cnt/sense, dec cnt/sense)

__device__ __forceinline__ float b2f(u16 b){
  unsigned int u = ((unsigned int)b) << 16;
  return __builtin_bit_cast(float, u);
}
__device__ __forceinline__ u16 f2b(float x){
  unsigned int u = __builtin_bit_cast(unsigned int, x);
  unsigned int lsb = (u >> 16) & 1u;
  u += 0x7fffu + lsb;
  return (u16)(u >> 16);
}
__device__ __forceinline__ float sigf(float x){ return 1.0f/(1.0f + __expf(-x)); }
__device__ __forceinline__ float tanhc(float x){
  x = fminf(15.0f, fmaxf(-15.0f, x));
  float e = __expf(2.0f*x);
  return (e - 1.0f) / (e + 1.0f);
}

union U8 { u16 s[8]; int4 v; };
union U4 { u16 s[4]; int2 v; };

// software grid barrier: requires all wgs co-resident (1 wg/CU via LDS, grid=256)
__device__ __forceinline__ void gbar(unsigned* cnt, unsigned* sense, unsigned nwg, unsigned& lsense){
  __syncthreads();
  if (threadIdx.x == 0){
    unsigned s = lsense ^ 1u;
    lsense = s;
    unsigned prev = __hip_atomic_fetch_add(cnt, 1u, __ATOMIC_ACQ_REL, __HIP_MEMORY_SCOPE_AGENT);
    if (prev == nwg - 1u){
      __hip_atomic_store(cnt, 0u, __ATOMIC_RELAXED, __HIP_MEMORY_SCOPE_AGENT);
      __hip_atomic_store(sense, s, __ATOMIC_RELEASE, __HIP_MEMORY_SCOPE_AGENT);
    } else {
      while (__hip_atomic_load(sense, __ATOMIC_RELAXED, __HIP_MEMORY_SCOPE_AGENT) != s){
        __builtin_amdgcn_s_sleep(2);
      }
      __builtin_amdgcn_fence(__ATOMIC_ACQUIRE, "agent");
    }
  }
  __syncthreads();
}

// ---------------- prep: weights -> bf16 MFMA B-fragment order ----------------
__global__ void prep_weights(
    const float* __restrict__ Wih_f, const float* __restrict__ Whh_f,
    const float* __restrict__ Wih_b, const float* __restrict__ Whh_b,
    const float* __restrict__ Wih_d, const float* __restrict__ Whh_d,
    const float* __restrict__ W_out,
    u16* __restrict__ encW, u16* __restrict__ decW, u16* __restrict__ woutW)
{
  const int total = ENC_TOT + DEC_TOT + WOUT_TOT;
  for (int idx = blockIdx.x*blockDim.x + threadIdx.x; idx < total; idx += gridDim.x*blockDim.x){
    if (idx < ENC_TOT){
      // [dir][cg(16)][gate(4)][kt(24)][nt(2)][512]
      int dir = idx / 1572864;
      int r0  = idx - dir*1572864;
      int cg  = r0 / 98304;  int r1 = r0 - cg*98304;
      int g   = r1 / 24576;  int r2 = r1 - g*24576;
      int kt  = r2 / 1024;   int r3 = r2 - kt*1024;
      int nt  = r3 >> 9;     int li = r3 & 511;
      int l = li >> 3, i = li & 7;
      int k   = kt*32 + ((l>>4)<<3) + i;
      int col = g*512 + cg*32 + nt*16 + (l&15);
      const float* Wih = dir ? Wih_b : Wih_f;
      const float* Whh = dir ? Whh_b : Whh_f;
      float v = (k < 256) ? Wih[col*256 + k] : Whh[col*512 + (k-256)];
      encW[idx] = f2b(v);
    } else if (idx < ENC_TOT + DEC_TOT){
      // [cg(32)][gate(4)][kt(28)][512]
      int id = idx - ENC_TOT;
      int cg = id / 57344;   int r1 = id - cg*57344;
      int g  = r1 / 14336;   int r2 = r1 - g*14336;
      int kt = r2 >> 9;      int li = r2 & 511;
      int l = li >> 3, i = li & 7;
      int k   = kt*32 + ((l>>4)<<3) + i;
      int col = g*512 + cg*16 + (l&15);
      float v = (k < 384) ? Wih_d[col*384 + k] : Whh_d[col*512 + (k-384)];
      decW[id] = f2b(v);
    } else {
      // [w(4)][kt(16)][512]
      int id = idx - ENC_TOT - DEC_TOT;
      int w  = id >> 13;  int r1 = id & 8191;
      int kt = r1 >> 9;   int li = r1 & 511;
      int l = li >> 3, i = li & 7;
      int k  = kt*32 + ((l>>4)<<3) + i;
      int vv = w*16 + (l&15);
      woutW[id] = f2b(W_out[vv*512 + k]);
    }
  }
}

__global__ void prep_zero(int4* __restrict__ henc, unsigned* __restrict__ bar){
  const int n = (2*2*BB*HH*2)/16;
  int4 z = make_int4(0,0,0,0);
  for (int i = blockIdx.x*blockDim.x + threadIdx.x; i < n; i += gridDim.x*blockDim.x)
    henc[i] = z;
  if (blockIdx.x == 0 && threadIdx.x < 4) bar[threadIdx.x] = 0u;
}

// ---------------- encoder: bidirectional LSTM, 128 steps, grid-resident ----------------
__global__ __launch_bounds__(256, 1) void encoder_kernel(
    const int* __restrict__ xseq, const float* __restrict__ emb,
    const float* __restrict__ b_f, const float* __restrict__ b_b,
    const u16* __restrict__ encW, u16* __restrict__ h_enc, unsigned* __restrict__ bar)
{
  __shared__ u16  sA[64*PITCH_E];
  __shared__ float sG[4*64*34];
  const int tid  = threadIdx.x;
  const int wave = tid >> 6, lane = tid & 63;
  const int bid  = blockIdx.x;
  const int bg   = bid & 7;          // batch group -> XCD
  const int dir  = (bid >> 3) & 1;
  const int cg   = bid >> 4;         // 0..15 column (unit) group
  const int ml   = lane & 15;
  const int kh   = (lane >> 4) * 8;
  const int rowb = (lane >> 4) * 4;

  // weights -> registers (once)
  bf16x8 wf[24][2];
  {
    const u16* wb = encW + (size_t)(((dir*16 + cg)*4 + wave)*48)*512 + lane*8;
    #pragma unroll
    for (int kt=0;kt<24;kt++)
      #pragma unroll
      for (int nt=0;nt<2;nt++)
        wf[kt][nt] = *(const bf16x8*)(wb + (kt*2+nt)*512);
  }
  const float* bias = dir ? b_b : b_f;
  float bval[2];
  #pragma unroll
  for (int nt=0;nt<2;nt++) bval[nt] = bias[wave*512 + cg*32 + nt*16 + ml];

  float c8[8];
  #pragma unroll
  for (int p=0;p<8;p++) c8[p] = 0.f;
  const int erow = tid >> 2;
  const int eug  = (tid & 3) * 8;
  const int sr = tid >> 2, sq = tid & 3;
  const int brow = bg*64 + sr;
  unsigned lsense = 0;

  #pragma unroll 1
  for (int t=0; t<TT; t++){
    const int cur = t & 1, nxt = cur ^ 1;
    const int t_eff = dir ? (TT-1-t) : t;
    // stage embedding (gather) + h into LDS A = [x_t | h]
    {
      const int xi = xseq[brow*TT + t_eff];
      const float* ep = emb + xi*EE + sq*64;
      u16* dst = &sA[sr*PITCH_E + sq*64];
      #pragma unroll
      for (int j=0;j<8;j++){
        float4 f0 = *(const float4*)(ep + j*8);
        float4 f1 = *(const float4*)(ep + j*8 + 4);
        U8 u;
        u.s[0]=f2b(f0.x); u.s[1]=f2b(f0.y); u.s[2]=f2b(f0.z); u.s[3]=f2b(f0.w);
        u.s[4]=f2b(f1.x); u.s[5]=f2b(f1.y); u.s[6]=f2b(f1.z); u.s[7]=f2b(f1.w);
        *(int4*)(dst + j*8) = u.v;
      }
      const u16* hp = h_enc + ((size_t)((dir*2 + cur)*BB) + brow)*HH + sq*128;
      u16* dsth = &sA[sr*PITCH_E + 256 + sq*128];
      #pragma unroll
      for (int j=0;j<16;j++)
        *(int4*)(dsth + j*8) = *(const int4*)(hp + j*8);
    }
    __syncthreads();
    // gate GEMM: [64 x 768] @ Wslice[768 x 128] (wave = one gate's 32 units)
    f32x4 acc[4][2];
    #pragma unroll
    for (int mt=0;mt<4;mt++)
      #pragma unroll
      for (int nt=0;nt<2;nt++)
        acc[mt][nt] = (f32x4){0.f,0.f,0.f,0.f};
    #pragma unroll
    for (int kt=0;kt<24;kt++){
      bf16x8 a[4];
      #pragma unroll
      for (int mt=0;mt<4;mt++)
        a[mt] = *(const bf16x8*)&sA[(mt*16 + ml)*PITCH_E + kt*32 + kh];
      #pragma unroll
      for (int mt=0;mt<4;mt++)
        #pragma unroll
        for (int nt=0;nt<2;nt++)
          acc[mt][nt] = __builtin_amdgcn_mfma_f32_16x16x32_bf16(a[mt], wf[kt][nt], acc[mt][nt], 0,0,0);
    }
    // exchange gates via LDS
    #pragma unroll
    for (int mt=0;mt<4;mt++)
      #pragma unroll
      for (int nt=0;nt<2;nt++)
        #pragma unroll
        for (int r=0;r<4;r++)
          sG[(wave*64 + mt*16 + rowb + r)*34 + nt*16 + ml] = acc[mt][nt][r] + bval[nt];
    __syncthreads();
    // elementwise LSTM cell: thread owns 8 (row,unit) cells
    {
      U8 u;
      #pragma unroll
      for (int p=0;p<8;p++){
        const int uu = eug + p;
        float gi = sG[(      erow)*34 + uu];
        float gf = sG[( 64 + erow)*34 + uu];
        float gg = sG[(128 + erow)*34 + uu];
        float go = sG[(192 + erow)*34 + uu];
        float c = sigf(gf)*c8[p] + sigf(gi)*tanhc(gg);
        c8[p] = c;
        u.s[p] = f2b(sigf(go)*tanhc(c));
      }
      u16* hd = h_enc + ((size_t)((dir*2 + nxt)*BB) + bg*64 + erow)*HH + cg*32 + eug;
      *(int4*)hd = u.v;
    }
    gbar(bar, bar+1, 256u, lsense);
  }
}

// ---------------- latent: mu/logvar/z/h0 ----------------
__global__ __launch_bounds__(256) void latent_kernel(
    const float* __restrict__ eps,
    const float* __restrict__ W_mu, const float* __restrict__ b_mu,
    const float* __restrict__ W_lv, const float* __restrict__ b_lv,
    const float* __restrict__ W_di, const float* __restrict__ b_di,
    const u16* __restrict__ h_enc, u16* __restrict__ h_dec0,
    u16* __restrict__ z_bf, float* __restrict__ outp)
{
  __shared__ float hc[16][1024];
  __shared__ float lvs[16][128];
  __shared__ float zs[16][128];
  const int tid = threadIdx.x;
  const int r0 = blockIdx.x * 16;
  for (int s = tid; s < 16*1024; s += 256){
    int r = s >> 10, k = s & 1023;
    float v = (k < 512)
      ? b2f(h_enc[(size_t)(r0 + r)*HH + k])                 // fwd final (dir0 buf0)
      : b2f(h_enc[(size_t)(2*BB + r0 + r)*HH + (k - 512)]); // bwd final (dir1 buf0)
    hc[r][k] = v;
  }
  __syncthreads();
  float acc[16];
  #pragma unroll
  for (int r=0;r<16;r++) acc[r] = 0.f;
  const float* wrow = (tid < 128) ? (W_mu + (size_t)tid*1024) : (W_lv + (size_t)(tid-128)*1024);
  for (int k=0;k<1024;k++){
    float w = wrow[k];
    #pragma unroll
    for (int r=0;r<16;r++) acc[r] += w * hc[r][k];
  }
  const float bb_ = (tid < 128) ? b_mu[tid] : b_lv[tid-128];
  if (tid >= 128){
    const int j = tid - 128;
    #pragma unroll
    for (int r=0;r<16;r++){
      float lv = acc[r] + bb_;
      outp[4259840u + (size_t)(r0+r)*LL + j] = lv;
      lvs[r][j] = lv;
    }
  }
  __syncthreads();
  if (tid < 128){
    const int j = tid;
    #pragma unroll
    for (int r=0;r<16;r++){
      float mu = acc[r] + bb_;
      outp[4194304u + (size_t)(r0+r)*LL + j] = mu;
      float z = mu + eps[(size_t)(r0+r)*LL + j] * __expf(0.5f * lvs[r][j]);
      zs[r][j] = z;
      z_bf[(size_t)(r0+r)*LL + j] = f2b(z);
    }
  }
  __syncthreads();
  float a1[16], a2[16];
  #pragma unroll
  for (int r=0;r<16;r++){ a1[r]=0.f; a2[r]=0.f; }
  const float* w1 = W_di + (size_t)tid*LL;
  const float* w2 = W_di + (size_t)(tid+256)*LL;
  for (int k=0;k<LL;k++){
    float x1 = w1[k], x2 = w2[k];
    #pragma unroll
    for (int r=0;r<16;r++){ a1[r] += x1*zs[r][k]; a2[r] += x2*zs[r][k]; }
  }
  const float bd1 = b_di[tid], bd2 = b_di[tid+256];
  #pragma unroll
  for (int r=0;r<16;r++){
    h_dec0[(size_t)(r0+r)*HH + tid]       = f2b(a1[r] + bd1);
    h_dec0[(size_t)(r0+r)*HH + tid + 256] = f2b(a2[r] + bd2);
  }
}

// ---------------- decoder LSTM, 128 steps, writes hs ----------------
__global__ __launch_bounds__(256, 1) void decoder_kernel(
    const int* __restrict__ tseq, const float* __restrict__ emb,
    const float* __restrict__ b_d, const u16* __restrict__ decW,
    const u16* __restrict__ z_bf, u16* __restrict__ h_dec,
    u16* __restrict__ hs, unsigned* __restrict__ bar)
{
  __shared__ u16  sA[64*PITCH_D];
  __shared__ float sG[4*64*18];
  const int tid  = threadIdx.x;
  const int wave = tid >> 6, lane = tid & 63;
  const int bid  = blockIdx.x;
  const int bg   = bid & 7;
  const int cg   = bid >> 3;   // 0..31, 16 units each
  const int ml   = lane & 15;
  const int kh   = (lane >> 4) * 8;
  const int rowb = (lane >> 4) * 4;

  bf16x8 wf[28];
  {
    const u16* wb = decW + (size_t)((cg*4 + wave)*28)*512 + lane*8;
    #pragma unroll
    for (int kt=0;kt<28;kt++)
      wf[kt] = *(const bf16x8*)(wb + kt*512);
  }
  const float bval = b_d[wave*512 + cg*16 + ml];
  float c4[4];
  #pragma unroll
  for (int p=0;p<4;p++) c4[p] = 0.f;
  const int erow = tid >> 2;
  const int eug  = (tid & 3) * 4;
  const int sr = tid >> 2, sq = tid & 3;
  const int brow = bg*64 + sr;
  unsigned lsense = 0;

  #pragma unroll 1
  for (int t=0; t<TT; t++){
    const int cur = t & 1, nxt = cur ^ 1;
    // stage A = [te_t | z | h]
    {
      const int xi = tseq[brow*TT + t];
      const float* ep = emb + xi*EE + sq*64;
      u16* dst = &sA[sr*PITCH_D + sq*64];
      #pragma unroll
      for (int j=0;j<8;j++){
        float4 f0 = *(const float4*)(ep + j*8);
        float4 f1 = *(const float4*)(ep + j*8 + 4);
        U8 u;
        u.s[0]=f2b(f0.x); u.s[1]=f2b(f0.y); u.s[2]=f2b(f0.z); u.s[3]=f2b(f0.w);
        u.s[4]=f2b(f1.x); u.s[5]=f2b(f1.y); u.s[6]=f2b(f1.z); u.s[7]=f2b(f1.w);
        *(int4*)(dst + j*8) = u.v;
      }
      const u16* zp = z_bf + brow*LL + sq*32;
      u16* dstz = &sA[sr*PITCH_D + 256 + sq*32];
      #pragma unroll
      for (int j=0;j<4;j++)
        *(int4*)(dstz + j*8) = *(const int4*)(zp + j*8);
      const u16* hp = h_dec + ((size_t)(cur*BB) + brow)*HH + sq*128;
      u16* dsth = &sA[sr*PITCH_D + 384 + sq*128];
      #pragma unroll
      for (int j=0;j<16;j++)
        *(int4*)(dsth + j*8) = *(const int4*)(hp + j*8);
    }
    __syncthreads();
    f32x4 acc[4];
    #pragma unroll
    for (int mt=0;mt<4;mt++) acc[mt] = (f32x4){0.f,0.f,0.f,0.f};
    #pragma unroll
    for (int kt=0;kt<28;kt++){
      bf16x8 a[4];
      #pragma unroll
      for (int mt=0;mt<4;mt++)
        a[mt] = *(const bf16x8*)&sA[(mt*16 + ml)*PITCH_D + kt*32 + kh];
      #pragma unroll
      for (int mt=0;mt<4;mt++)
        acc[mt] = __builtin_amdgcn_mfma_f32_16x16x32_bf16(a[mt], wf[kt], acc[mt], 0,0,0);
    }
    #pragma unroll
    for (int mt=0;mt<4;mt++)
      #pragma unroll
      for (int r=0;r<4;r++)
        sG[(wave*64 + mt*16 + rowb + r)*18 + ml] = acc[mt][r] + bval;
    __syncthreads();
    {
      U4 u;
      #pragma unroll
      for (int p=0;p<4;p++){
        const int uu = eug + p;
        float gi = sG[(      erow)*18 + uu];
        float gf = sG[( 64 + erow)*18 + uu];
        float gg = sG[(128 + erow)*18 + uu];
        float go = sG[(192 + erow)*18 + uu];
        float c = sigf(gf)*c4[p] + sigf(gi)*tanhc(gg);
        c4[p] = c;
        u.s[p] = f2b(sigf(go)*tanhc(c));
      }
      u16* hd1 = h_dec + ((size_t)(nxt*BB) + bg*64 + erow)*HH + cg*16 + eug;
      *(int2*)hd1 = u.v;
      u16* hd2 = hs + ((size_t)t*BB + bg*64 + erow)*HH + cg*16 + eug;
      *(int2*)hd2 = u.v;
    }
    gbar(bar, bar+1, 256u, lsense);
  }
}

// ---------------- recon: [65536,512] @ W_out^T[512,64] + b_out ----------------
__global__ __launch_bounds__(256) void recon_kernel(
    const u16* __restrict__ hs, const u16* __restrict__ woutW,
    const float* __restrict__ b_out, float* __restrict__ outp)
{
  __shared__ u16 sA[64*PITCH_R];
  const int tid  = threadIdx.x;
  const int wave = tid >> 6, lane = tid & 63;
  const int row0 = blockIdx.x * 64;
  const int ml = lane & 15;
  const int kh = (lane >> 4) * 8;
  {
    const int sr = tid >> 2, sq = tid & 3;
    const u16* hp = hs + (size_t)(row0 + sr)*HH + sq*128;
    u16* dst = &sA[sr*PITCH_R + sq*128];
    #pragma unroll
    for (int j=0;j<16;j++)
      *(int4*)(dst + j*8) = *(const int4*)(hp + j*8);
  }
  bf16x8 wf[16];
  #pragma unroll
  for (int kt=0;kt<16;kt++)
    wf[kt] = *(const bf16x8*)(woutW + ((wave*16 + kt) << 9) + lane*8);
  __syncthreads();
  f32x4 acc[4];
  #pragma unroll
  for (int mt=0;mt<4;mt++) acc[mt] = (f32x4){0.f,0.f,0.f,0.f};
  #pragma unroll
  for (int kt=0;kt<16;kt++){
    #pragma unroll
    for (int mt=0;mt<4;mt++){
      bf16x8 a = *(const bf16x8*)&sA[(mt*16 + ml)*PITCH_R + kt*32 + kh];
      acc[mt] = __builtin_amdgcn_mfma_f32_16x16x32_bf16(a, wf[kt], acc[mt], 0,0,0);
    }
  }
  const float bo = b_out[wave*16 + ml];
  #pragma unroll
  for (int mt=0;mt<4;mt++)
    #pragma unroll
    for (int r=0;r<4;r++){
      int fr = row0 + mt*16 + ((lane>>4)<<2) + r;  // flat row = t*512 + b
      int tt = fr >> 9, b = fr & 511;
      outp[(size_t)(b*TT + tt)*VV + wave*16 + ml] = acc[mt][r] + bo;
    }
}

extern "C" void kernel_launch(void* const* d_in, const int* in_sizes, int n_in,
                              void* d_out, int out_size, void* d_ws, size_t ws_size,
                              hipStream_t stream)
{
  (void)in_sizes; (void)n_in; (void)out_size; (void)ws_size;
  const int*   x     = (const int*)d_in[0];
  const int*   tgt   = (const int*)d_in[1];
  const float* eps   = (const float*)d_in[2];
  const float* emb   = (const float*)d_in[3];
  const float* Wih_f = (const float*)d_in[4];
  const float* Whh_f = (const float*)d_in[5];
  const float* b_f   = (const float*)d_in[6];
  const float* Wih_b = (const float*)d_in[7];
  const float* Whh_b = (const float*)d_in[8];
  const float* b_b   = (const float*)d_in[9];
  const float* W_mu  = (const float*)d_in[10];
  const float* b_mu  = (const float*)d_in[11];
  const float* W_lv  = (const float*)d_in[12];
  const float* b_lv  = (const float*)d_in[13];
  const float* W_di  = (const float*)d_in[14];
  const float* b_di  = (const float*)d_in[15];
  const float* Wih_d = (const float*)d_in[16];
  const float* Whh_d = (const float*)d_in[17];
  const float* b_d   = (const float*)d_in[18];
  const float* W_out = (const float*)d_in[19];
  const float* b_out = (const float*)d_in[20];

  char* ws = (char*)d_ws;
  u16* encW  = (u16*)(ws + OFF_ENCW);
  u16* decW  = (u16*)(ws + OFF_DECW);
  u16* woutW = (u16*)(ws + OFF_WOUT);
  u16* henc  = (u16*)(ws + OFF_HENC);
  u16* hdec  = (u16*)(ws + OFF_HDEC);
  u16* zbf   = (u16*)(ws + OFF_ZBF);
  u16* hsbuf = (u16*)(ws + OFF_HS);
  unsigned* bar = (unsigned*)(ws + OFF_BAR);
  float* outp = (float*)d_out;

  prep_weights<<<2048, 256, 0, stream>>>(Wih_f, Whh_f, Wih_b, Whh_b, Wih_d, Whh_d, W_out,
                                         encW, decW, woutW);
  prep_zero<<<256, 256, 0, stream>>>((int4*)henc, bar);
  encoder_kernel<<<256, 256, 0, stream>>>(x, emb, b_f, b_b, encW, henc, bar);
  latent_kernel<<<32, 256, 0, stream>>>(eps, W_mu, b_mu, W_lv, b_lv, W_di, b_di,
                                        henc, hdec, zbf, outp);
  decoder_kernel<<<256, 256, 0, stream>>>(tgt, emb, b_d, decW, zbf, hdec, hsbuf, bar + 2);
  recon_kernel<<<1024, 256, 0, stream>>>(hsbuf, woutW, b_out, outp);
}

// Round 2
// 4204.288 us; speedup vs baseline: 1.7283x; 1.7283x over previous
//
#include <hip/hip_runtime.h>

#define BB 512
#define TT 128
#define VV 64
#define EE 256
#define HH 512
#define LL 128

typedef __bf16 bf16x8 __attribute__((ext_vector_type(8)));
typedef float f32x4 __attribute__((ext_vector_type(4)));
typedef unsigned short u16;

#define PITCH_E 792   // 768+24 elems; 396 dw, 396%32=12 -> good b128 tiling
#define PITCH_D 920   // 896+24; 460 dw %32 = 12
#define PITCH_R 536   // 512+24; 268 dw %32 = 12

// ---- workspace layout (bytes) ----
#define ENC_TOT  3145728   // enc weight frag elems (2 dirs x 768x2048)
#define DEC_TOT  1835008   // dec weight frag elems (896x2048)
#define WOUT_TOT 32768     // W_out frag elems (512x64)
#define EMB_TOT  16384     // emb bf16 elems
#define OFF_ENCW 0ull
#define OFF_DECW 6291456ull
#define OFF_WOUT 9961472ull
#define OFF_EMBB 10027008ull
#define OFF_HENC 10059776ull   // [2dir][2buf][512][512] bf16
#define OFF_HDEC 12156928ull   // [2buf][512][512] bf16
#define OFF_ZBF  13205504ull   // [512][128] bf16
#define OFF_HS   13336576ull   // [128][512][512] bf16
#define OFF_FLG  80445440ull   // [24][64] u32 flags (enc groups 0..15, dec 16..23)

__device__ __forceinline__ float b2f(u16 b){
  unsigned int u = ((unsigned int)b) << 16;
  return __builtin_bit_cast(float, u);
}
__device__ __forceinline__ u16 f2b(float x){
  unsigned int u = __builtin_bit_cast(unsigned int, x);
  unsigned int lsb = (u >> 16) & 1u;
  u += 0x7fffu + lsb;
  return (u16)(u >> 16);
}
__device__ __forceinline__ float sigf(float x){ return 1.0f/(1.0f + __expf(-x)); }
__device__ __forceinline__ float tanhc(float x){
  x = fminf(15.0f, fmaxf(-15.0f, x));
  float e = __expf(2.0f*x);
  return (e - 1.0f) / (e + 1.0f);
}

union U8 { u16 s[8]; int4 v; };
union U4 { u16 s[4]; int2 v; };

// ---------------- prep: weights -> bf16 MFMA B-fragment order; emb -> bf16 ----------------
__global__ void prep_weights(
    const float* __restrict__ Wih_f, const float* __restrict__ Whh_f,
    const float* __restrict__ Wih_b, const float* __restrict__ Whh_b,
    const float* __restrict__ Wih_d, const float* __restrict__ Whh_d,
    const float* __restrict__ W_out, const float* __restrict__ emb,
    u16* __restrict__ encW, u16* __restrict__ decW, u16* __restrict__ woutW,
    u16* __restrict__ embB)
{
  const int total = ENC_TOT + DEC_TOT + WOUT_TOT + EMB_TOT;
  for (int idx = blockIdx.x*blockDim.x + threadIdx.x; idx < total; idx += gridDim.x*blockDim.x){
    if (idx < ENC_TOT){
      // [dir][cg(16)][gate(4)][kt(24)][nt(2)][512]
      int dir = idx / 1572864;
      int r0  = idx - dir*1572864;
      int cg  = r0 / 98304;  int r1 = r0 - cg*98304;
      int g   = r1 / 24576;  int r2 = r1 - g*24576;
      int kt  = r2 / 1024;   int r3 = r2 - kt*1024;
      int nt  = r3 >> 9;     int li = r3 & 511;
      int l = li >> 3, i = li & 7;
      int k   = kt*32 + ((l>>4)<<3) + i;
      int col = g*512 + cg*32 + nt*16 + (l&15);
      const float* Wih = dir ? Wih_b : Wih_f;
      const float* Whh = dir ? Whh_b : Whh_f;
      float v = (k < 256) ? Wih[col*256 + k] : Whh[col*512 + (k-256)];
      encW[idx] = f2b(v);
    } else if (idx < ENC_TOT + DEC_TOT){
      // [cg(32)][gate(4)][kt(28)][512]
      int id = idx - ENC_TOT;
      int cg = id / 57344;   int r1 = id - cg*57344;
      int g  = r1 / 14336;   int r2 = r1 - g*14336;
      int kt = r2 >> 9;      int li = r2 & 511;
      int l = li >> 3, i = li & 7;
      int k   = kt*32 + ((l>>4)<<3) + i;
      int col = g*512 + cg*16 + (l&15);
      float v = (k < 384) ? Wih_d[col*384 + k] : Whh_d[col*512 + (k-384)];
      decW[id] = f2b(v);
    } else if (idx < ENC_TOT + DEC_TOT + WOUT_TOT){
      // [w(4)][kt(16)][512]
      int id = idx - ENC_TOT - DEC_TOT;
      int w  = id >> 13;  int r1 = id & 8191;
      int kt = r1 >> 9;   int li = r1 & 511;
      int l = li >> 3, i = li & 7;
      int k  = kt*32 + ((l>>4)<<3) + i;
      int vv = w*16 + (l&15);
      woutW[id] = f2b(W_out[vv*512 + k]);
    } else {
      int id = idx - ENC_TOT - DEC_TOT - WOUT_TOT;
      embB[id] = f2b(emb[id]);
    }
  }
}

__global__ void prep_zero(int4* __restrict__ henc, unsigned* __restrict__ flg){
  const int n = (2*2*BB*HH*2)/16;
  int4 z = make_int4(0,0,0,0);
  const int gid = blockIdx.x*blockDim.x + threadIdx.x;
  const int stride = gridDim.x*blockDim.x;
  for (int i = gid; i < n; i += stride) henc[i] = z;
  for (int i = gid; i < 24*64; i += stride) flg[i] = 0u;
}

// ---------------- encoder: bidirectional LSTM, 128 steps, grid-resident ----------------
// grid 256: bg = bid&7 (batch group, ->XCD), dir = (bid>>3)&1, cg = bid>>4 (unit group of 32)
// sync: per-(dir,bg) group of 16 wgs via monotonic flags
__global__ __launch_bounds__(256, 1) void encoder_kernel(
    const int* __restrict__ xseq, const u16* __restrict__ embB,
    const float* __restrict__ b_f, const float* __restrict__ b_b,
    const u16* __restrict__ encW, u16* __restrict__ h_enc, unsigned* __restrict__ flg)
{
  __shared__ u16  sA[64*PITCH_E];
  __shared__ float sG[4*64*34];
  const int tid  = threadIdx.x;
  const int wave = tid >> 6, lane = tid & 63;
  const int bid  = blockIdx.x;
  const int bg   = bid & 7;
  const int dir  = (bid >> 3) & 1;
  const int cg   = bid >> 4;
  const int ml   = lane & 15;
  const int kh   = (lane >> 4) * 8;
  const int rowb = (lane >> 4) * 4;

  unsigned* gflags = flg + (dir*8 + bg)*64;
  unsigned* myflag = gflags + cg;

  // weights -> registers (once)
  bf16x8 wf[24][2];
  {
    const u16* wb = encW + (size_t)(((dir*16 + cg)*4 + wave)*48)*512 + lane*8;
    #pragma unroll
    for (int kt=0;kt<24;kt++)
      #pragma unroll
      for (int nt=0;nt<2;nt++)
        wf[kt][nt] = *(const bf16x8*)(wb + (kt*2+nt)*512);
  }
  const float* bias = dir ? b_b : b_f;
  float bval[2];
  #pragma unroll
  for (int nt=0;nt<2;nt++) bval[nt] = bias[wave*512 + cg*32 + nt*16 + ml];

  float c8[8];
  #pragma unroll
  for (int p=0;p<8;p++) c8[p] = 0.f;
  const int brow = bg*64 + lane;   // this thread's staged/elementwise row

  // pre-stage emb for t=0: thread (wave,lane) -> row lane, emb chunk wave (64 elems)
  {
    const int t_eff0 = dir ? (TT-1) : 0;
    const int xi = xseq[brow*TT + t_eff0];
    const int4* ep = (const int4*)(embB + xi*EE + wave*64);
    int4* dst = (int4*)&sA[lane*PITCH_E + wave*64];
    #pragma unroll
    for (int j=0;j<8;j++) dst[j] = ep[j];
  }

  #pragma unroll 1
  for (int t=0; t<TT; t++){
    const int cur = t & 1, nxt = cur ^ 1;
    // wait: h(t) ready (group flags >= t; trivially true at t=0)
    if (wave == 0){
      if (lane < 16){
        while (__hip_atomic_load(gflags + lane, __ATOMIC_RELAXED, __HIP_MEMORY_SCOPE_AGENT) < (unsigned)t) { }
      }
      __builtin_amdgcn_fence(__ATOMIC_ACQUIRE, "agent");
    }
    __syncthreads();
    // stage h: row lane, chunk wave (128 elems)
    {
      const int4* hp = (const int4*)(h_enc + ((size_t)((dir*2 + cur)*BB) + brow)*HH + wave*128);
      int4* dsth = (int4*)&sA[lane*PITCH_E + 256 + wave*128];
      #pragma unroll
      for (int j=0;j<16;j++) dsth[j] = hp[j];
    }
    __syncthreads();
    // gate GEMM: [64 x 768] @ W[768 x 128]; wave = one gate's 32 units
    f32x4 acc[4][2];
    #pragma unroll
    for (int mt=0;mt<4;mt++)
      #pragma unroll
      for (int nt=0;nt<2;nt++)
        acc[mt][nt] = (f32x4){0.f,0.f,0.f,0.f};
    #pragma unroll
    for (int kt=0;kt<24;kt++){
      bf16x8 a[4];
      #pragma unroll
      for (int mt=0;mt<4;mt++)
        a[mt] = *(const bf16x8*)&sA[(mt*16 + ml)*PITCH_E + kt*32 + kh];
      #pragma unroll
      for (int mt=0;mt<4;mt++)
        #pragma unroll
        for (int nt=0;nt<2;nt++)
          acc[mt][nt] = __builtin_amdgcn_mfma_f32_16x16x32_bf16(a[mt], wf[kt][nt], acc[mt][nt], 0,0,0);
    }
    #pragma unroll
    for (int mt=0;mt<4;mt++)
      #pragma unroll
      for (int nt=0;nt<2;nt++)
        #pragma unroll
        for (int r=0;r<4;r++)
          sG[(wave*64 + mt*16 + rowb + r)*34 + nt*16 + ml] = acc[mt][nt][r] + bval[nt];
    __syncthreads();
    // elementwise: thread (wave,lane) -> row lane, units [wave*8, wave*8+8)
    {
      U8 u;
      #pragma unroll
      for (int p=0;p<8;p++){
        const int uu = wave*8 + p;
        float gi = sG[(      lane)*34 + uu];
        float gf = sG[( 64 + lane)*34 + uu];
        float gg = sG[(128 + lane)*34 + uu];
        float go = sG[(192 + lane)*34 + uu];
        float c = sigf(gf)*c8[p] + sigf(gi)*tanhc(gg);
        c8[p] = c;
        u.s[p] = f2b(sigf(go)*tanhc(c));
      }
      u16* hd = h_enc + ((size_t)((dir*2 + nxt)*BB) + brow)*HH + cg*32 + wave*8;
      *(int4*)hd = u.v;
    }
    __syncthreads();   // all h stores drained (vmcnt(0) at barrier)
    if (tid == 0)
      __hip_atomic_store(myflag, (unsigned)(t+1), __ATOMIC_RELEASE, __HIP_MEMORY_SCOPE_AGENT);
    // overlap: stage next step's embedding while group peers finish
    if (t+1 < TT){
      const int t_eff = dir ? (TT-2-t) : (t+1);
      const int xi = xseq[brow*TT + t_eff];
      const int4* ep = (const int4*)(embB + xi*EE + wave*64);
      int4* dst = (int4*)&sA[lane*PITCH_E + wave*64];
      #pragma unroll
      for (int j=0;j<8;j++) dst[j] = ep[j];
    }
  }
}

// ---------------- latent: mu/logvar/z/h0 ----------------
__global__ __launch_bounds__(256) void latent_kernel(
    const float* __restrict__ eps,
    const float* __restrict__ W_mu, const float* __restrict__ b_mu,
    const float* __restrict__ W_lv, const float* __restrict__ b_lv,
    const float* __restrict__ W_di, const float* __restrict__ b_di,
    const u16* __restrict__ h_enc, u16* __restrict__ h_dec0,
    u16* __restrict__ z_bf, float* __restrict__ outp)
{
  __shared__ float hc[16][1024];
  __shared__ float lvs[16][128];
  __shared__ float zs[16][128];
  const int tid = threadIdx.x;
  const int r0 = blockIdx.x * 16;
  for (int s = tid; s < 16*1024; s += 256){
    int r = s >> 10, k = s & 1023;
    float v = (k < 512)
      ? b2f(h_enc[(size_t)(r0 + r)*HH + k])                 // fwd final (dir0 buf0)
      : b2f(h_enc[(size_t)(2*BB + r0 + r)*HH + (k - 512)]); // bwd final (dir1 buf0)
    hc[r][k] = v;
  }
  __syncthreads();
  float acc[16];
  #pragma unroll
  for (int r=0;r<16;r++) acc[r] = 0.f;
  const float* wrow = (tid < 128) ? (W_mu + (size_t)tid*1024) : (W_lv + (size_t)(tid-128)*1024);
  for (int k=0;k<1024;k++){
    float w = wrow[k];
    #pragma unroll
    for (int r=0;r<16;r++) acc[r] += w * hc[r][k];
  }
  const float bb_ = (tid < 128) ? b_mu[tid] : b_lv[tid-128];
  if (tid >= 128){
    const int j = tid - 128;
    #pragma unroll
    for (int r=0;r<16;r++){
      float lv = acc[r] + bb_;
      outp[4259840u + (size_t)(r0+r)*LL + j] = lv;
      lvs[r][j] = lv;
    }
  }
  __syncthreads();
  if (tid < 128){
    const int j = tid;
    #pragma unroll
    for (int r=0;r<16;r++){
      float mu = acc[r] + bb_;
      outp[4194304u + (size_t)(r0+r)*LL + j] = mu;
      float z = mu + eps[(size_t)(r0+r)*LL + j] * __expf(0.5f * lvs[r][j]);
      zs[r][j] = z;
      z_bf[(size_t)(r0+r)*LL + j] = f2b(z);
    }
  }
  __syncthreads();
  float a1[16], a2[16];
  #pragma unroll
  for (int r=0;r<16;r++){ a1[r]=0.f; a2[r]=0.f; }
  const float* w1 = W_di + (size_t)tid*LL;
  const float* w2 = W_di + (size_t)(tid+256)*LL;
  for (int k=0;k<LL;k++){
    float x1 = w1[k], x2 = w2[k];
    #pragma unroll
    for (int r=0;r<16;r++){ a1[r] += x1*zs[r][k]; a2[r] += x2*zs[r][k]; }
  }
  const float bd1 = b_di[tid], bd2 = b_di[tid+256];
  #pragma unroll
  for (int r=0;r<16;r++){
    h_dec0[(size_t)(r0+r)*HH + tid]       = f2b(a1[r] + bd1);
    h_dec0[(size_t)(r0+r)*HH + tid + 256] = f2b(a2[r] + bd2);
  }
}

// ---------------- decoder LSTM, 128 steps, writes hs ----------------
// grid 256: bg = bid&7, cg = bid>>3 (unit group of 16); sync per-bg group of 32 wgs
__global__ __launch_bounds__(256, 1) void decoder_kernel(
    const int* __restrict__ tseq, const u16* __restrict__ embB,
    const float* __restrict__ b_d, const u16* __restrict__ decW,
    const u16* __restrict__ z_bf, u16* __restrict__ h_dec,
    u16* __restrict__ hs, unsigned* __restrict__ flg)
{
  __shared__ u16  sA[64*PITCH_D];
  __shared__ float sG[4*64*18];
  const int tid  = threadIdx.x;
  const int wave = tid >> 6, lane = tid & 63;
  const int bid  = blockIdx.x;
  const int bg   = bid & 7;
  const int cg   = bid >> 3;
  const int ml   = lane & 15;
  const int kh   = (lane >> 4) * 8;
  const int rowb = (lane >> 4) * 4;

  unsigned* gflags = flg + bg*64;
  unsigned* myflag = gflags + cg;

  bf16x8 wf[28];
  {
    const u16* wb = decW + (size_t)((cg*4 + wave)*28)*512 + lane*8;
    #pragma unroll
    for (int kt=0;kt<28;kt++)
      wf[kt] = *(const bf16x8*)(wb + kt*512);
  }
  const float bval = b_d[wave*512 + cg*16 + ml];
  float c4[4];
  #pragma unroll
  for (int p=0;p<4;p++) c4[p] = 0.f;
  const int brow = bg*64 + lane;

  // stage z once (constant over t): row lane, chunk wave (32 elems)
  {
    const int4* zp = (const int4*)(z_bf + brow*LL + wave*32);
    int4* dstz = (int4*)&sA[lane*PITCH_D + 256 + wave*32];
    #pragma unroll
    for (int j=0;j<4;j++) dstz[j] = zp[j];
  }
  // pre-stage emb for t=0
  {
    const int xi = tseq[brow*TT + 0];
    const int4* ep = (const int4*)(embB + xi*EE + wave*64);
    int4* dst = (int4*)&sA[lane*PITCH_D + wave*64];
    #pragma unroll
    for (int j=0;j<8;j++) dst[j] = ep[j];
  }

  #pragma unroll 1
  for (int t=0; t<TT; t++){
    const int cur = t & 1, nxt = cur ^ 1;
    if (wave == 0){
      if (lane < 32){
        while (__hip_atomic_load(gflags + lane, __ATOMIC_RELAXED, __HIP_MEMORY_SCOPE_AGENT) < (unsigned)t) { }
      }
      __builtin_amdgcn_fence(__ATOMIC_ACQUIRE, "agent");
    }
    __syncthreads();
    // stage h: row lane, chunk wave (128 elems)
    {
      const int4* hp = (const int4*)(h_dec + ((size_t)(cur*BB) + brow)*HH + wave*128);
      int4* dsth = (int4*)&sA[lane*PITCH_D + 384 + wave*128];
      #pragma unroll
      for (int j=0;j<16;j++) dsth[j] = hp[j];
    }
    __syncthreads();
    f32x4 acc[4];
    #pragma unroll
    for (int mt=0;mt<4;mt++) acc[mt] = (f32x4){0.f,0.f,0.f,0.f};
    #pragma unroll
    for (int kt=0;kt<28;kt++){
      bf16x8 a[4];
      #pragma unroll
      for (int mt=0;mt<4;mt++)
        a[mt] = *(const bf16x8*)&sA[(mt*16 + ml)*PITCH_D + kt*32 + kh];
      #pragma unroll
      for (int mt=0;mt<4;mt++)
        acc[mt] = __builtin_amdgcn_mfma_f32_16x16x32_bf16(a[mt], wf[kt], acc[mt], 0,0,0);
    }
    #pragma unroll
    for (int mt=0;mt<4;mt++)
      #pragma unroll
      for (int r=0;r<4;r++)
        sG[(wave*64 + mt*16 + rowb + r)*18 + ml] = acc[mt][r] + bval;
    __syncthreads();
    // elementwise: row lane, units [wave*4, wave*4+4)
    {
      U4 u;
      #pragma unroll
      for (int p=0;p<4;p++){
        const int uu = wave*4 + p;
        float gi = sG[(      lane)*18 + uu];
        float gf = sG[( 64 + lane)*18 + uu];
        float gg = sG[(128 + lane)*18 + uu];
        float go = sG[(192 + lane)*18 + uu];
        float c = sigf(gf)*c4[p] + sigf(gi)*tanhc(gg);
        c4[p] = c;
        u.s[p] = f2b(sigf(go)*tanhc(c));
      }
      u16* hd1 = h_dec + ((size_t)(nxt*BB) + brow)*HH + cg*16 + wave*4;
      *(int2*)hd1 = u.v;
      u16* hd2 = hs + ((size_t)t*BB + brow)*HH + cg*16 + wave*4;
      *(int2*)hd2 = u.v;
    }
    __syncthreads();
    if (tid == 0)
      __hip_atomic_store(myflag, (unsigned)(t+1), __ATOMIC_RELEASE, __HIP_MEMORY_SCOPE_AGENT);
    if (t+1 < TT){
      const int xi = tseq[brow*TT + (t+1)];
      const int4* ep = (const int4*)(embB + xi*EE + wave*64);
      int4* dst = (int4*)&sA[lane*PITCH_D + wave*64];
      #pragma unroll
      for (int j=0;j<8;j++) dst[j] = ep[j];
    }
  }
}

// ---------------- recon: [65536,512] @ W_out^T[512,64] + b_out ----------------
__global__ __launch_bounds__(256) void recon_kernel(
    const u16* __restrict__ hs, const u16* __restrict__ woutW,
    const float* __restrict__ b_out, float* __restrict__ outp)
{
  __shared__ u16 sA[64*PITCH_R];
  const int tid  = threadIdx.x;
  const int wave = tid >> 6, lane = tid & 63;
  const int row0 = blockIdx.x * 64;
  const int ml = lane & 15;
  const int kh = (lane >> 4) * 8;
  {
    // row lane, chunk wave (128 elems)
    const int4* hp = (const int4*)(hs + (size_t)(row0 + lane)*HH + wave*128);
    int4* dst = (int4*)&sA[lane*PITCH_R + wave*128];
    #pragma unroll
    for (int j=0;j<16;j++) dst[j] = hp[j];
  }
  bf16x8 wf[16];
  #pragma unroll
  for (int kt=0;kt<16;kt++)
    wf[kt] = *(const bf16x8*)(woutW + ((wave*16 + kt) << 9) + lane*8);
  __syncthreads();
  f32x4 acc[4];
  #pragma unroll
  for (int mt=0;mt<4;mt++) acc[mt] = (f32x4){0.f,0.f,0.f,0.f};
  #pragma unroll
  for (int kt=0;kt<16;kt++){
    #pragma unroll
    for (int mt=0;mt<4;mt++){
      bf16x8 a = *(const bf16x8*)&sA[(mt*16 + ml)*PITCH_R + kt*32 + kh];
      acc[mt] = __builtin_amdgcn_mfma_f32_16x16x32_bf16(a, wf[kt], acc[mt], 0,0,0);
    }
  }
  const float bo = b_out[wave*16 + ml];
  #pragma unroll
  for (int mt=0;mt<4;mt++)
    #pragma unroll
    for (int r=0;r<4;r++){
      int fr = row0 + mt*16 + ((lane>>4)<<2) + r;  // flat row = t*512 + b
      int tt = fr >> 9, b = fr & 511;
      outp[(size_t)(b*TT + tt)*VV + wave*16 + ml] = acc[mt][r] + bo;
    }
}

extern "C" void kernel_launch(void* const* d_in, const int* in_sizes, int n_in,
                              void* d_out, int out_size, void* d_ws, size_t ws_size,
                              hipStream_t stream)
{
  (void)in_sizes; (void)n_in; (void)out_size; (void)ws_size;
  const int*   x     = (const int*)d_in[0];
  const int*   tgt   = (const int*)d_in[1];
  const float* eps   = (const float*)d_in[2];
  const float* emb   = (const float*)d_in[3];
  const float* Wih_f = (const float*)d_in[4];
  const float* Whh_f = (const float*)d_in[5];
  const float* b_f   = (const float*)d_in[6];
  const float* Wih_b = (const float*)d_in[7];
  const float* Whh_b = (const float*)d_in[8];
  const float* b_b   = (const float*)d_in[9];
  const float* W_mu  = (const float*)d_in[10];
  const float* b_mu  = (const float*)d_in[11];
  const float* W_lv  = (const float*)d_in[12];
  const float* b_lv  = (const float*)d_in[13];
  const float* W_di  = (const float*)d_in[14];
  const float* b_di  = (const float*)d_in[15];
  const float* Wih_d = (const float*)d_in[16];
  const float* Whh_d = (const float*)d_in[17];
  const float* b_d   = (const float*)d_in[18];
  const float* W_out = (const float*)d_in[19];
  const float* b_out = (const float*)d_in[20];

  char* ws = (char*)d_ws;
  u16* encW  = (u16*)(ws + OFF_ENCW);
  u16* decW  = (u16*)(ws + OFF_DECW);
  u16* woutW = (u16*)(ws + OFF_WOUT);
  u16* embB  = (u16*)(ws + OFF_EMBB);
  u16* henc  = (u16*)(ws + OFF_HENC);
  u16* hdec  = (u16*)(ws + OFF_HDEC);
  u16* zbf   = (u16*)(ws + OFF_ZBF);
  u16* hsbuf = (u16*)(ws + OFF_HS);
  unsigned* flg = (unsigned*)(ws + OFF_FLG);
  float* outp = (float*)d_out;

  prep_weights<<<2048, 256, 0, stream>>>(Wih_f, Whh_f, Wih_b, Whh_b, Wih_d, Whh_d, W_out, emb,
                                         encW, decW, woutW, embB);
  prep_zero<<<256, 256, 0, stream>>>((int4*)henc, flg);
  encoder_kernel<<<256, 256, 0, stream>>>(x, embB, b_f, b_b, encW, henc, flg);
  latent_kernel<<<32, 256, 0, stream>>>(eps, W_mu, b_mu, W_lv, b_lv, W_di, b_di,
                                        henc, hdec, zbf, outp);
  decoder_kernel<<<256, 256, 0, stream>>>(tgt, embB, b_d, decW, zbf, hdec, hsbuf, flg + 16*64);
  recon_kernel<<<1024, 256, 0, stream>>>(hsbuf, woutW, b_out, outp);
}

// Round 3
// 3578.755 us; speedup vs baseline: 2.0304x; 1.1748x over previous
//
#include <hip/hip_runtime.h>

#define BB 512
#define TT 128
#define VV 64
#define EE 256
#define HH 512
#define LL 128

typedef __bf16 bf16x8 __attribute__((ext_vector_type(8)));
typedef float f32x4 __attribute__((ext_vector_type(4)));
typedef unsigned short u16;
typedef unsigned long long ull;

#define PITCH_E 792   // 768+24 elems; 396 dw %32 = 12 -> good b128 tiling
#define PITCH_D 920   // 896+24; 460 dw %32 = 12
#define PITCH_R 536   // 512+24; 268 dw %32 = 12

// ---- workspace layout (bytes) ----
#define ENC_TOT  3145728   // enc weight frag elems (2 dirs x 768x2048)
#define DEC_TOT  1835008   // dec weight frag elems (896x2048)
#define WOUT_TOT 32768     // W_out frag elems (512x64)
#define EMB_TOT  16384     // emb bf16 elems
#define OFF_ENCW 0ull
#define OFF_DECW 6291456ull
#define OFF_WOUT 9961472ull
#define OFF_EMBB 10027008ull
#define OFF_HENC 10059776ull   // [2dir][2buf][512][512] bf16
#define OFF_HDEC 12156928ull   // [2buf][512][512] bf16
#define OFF_ZBF  13205504ull   // [512][128] bf16
#define OFF_HS   13336576ull   // [128][512][512] bf16
#define OFF_FLG  80445440ull   // [24][64] u32 flags (enc groups 0..15, dec 16..23)

__device__ __forceinline__ float b2f(u16 b){
  unsigned int u = ((unsigned int)b) << 16;
  return __builtin_bit_cast(float, u);
}
__device__ __forceinline__ u16 f2b(float x){
  unsigned int u = __builtin_bit_cast(unsigned int, x);
  unsigned int lsb = (u >> 16) & 1u;
  u += 0x7fffu + lsb;
  return (u16)(u >> 16);
}
__device__ __forceinline__ float sigf(float x){ return 1.0f/(1.0f + __expf(-x)); }
__device__ __forceinline__ float tanhc(float x){
  x = fminf(15.0f, fmaxf(-15.0f, x));
  float e = __expf(2.0f*x);
  return (e - 1.0f) / (e + 1.0f);
}

// relaxed agent-scope coherent access (sc0 sc1, NO wbl2/inv fences)
__device__ __forceinline__ ull cload(const ull* p){
  return __hip_atomic_load(p, __ATOMIC_RELAXED, __HIP_MEMORY_SCOPE_AGENT);
}
__device__ __forceinline__ void cstore(ull* p, ull v){
  __hip_atomic_store(p, v, __ATOMIC_RELAXED, __HIP_MEMORY_SCOPE_AGENT);
}

union U8 { u16 s[8]; int4 v; ull q[2]; };
union U4 { u16 s[4]; int2 v; ull q; };
union P2 { ull q[2]; int4 v; };

// ---------------- prep: weights -> bf16 MFMA B-fragment order; emb -> bf16 ----------------
__global__ void prep_weights(
    const float* __restrict__ Wih_f, const float* __restrict__ Whh_f,
    const float* __restrict__ Wih_b, const float* __restrict__ Whh_b,
    const float* __restrict__ Wih_d, const float* __restrict__ Whh_d,
    const float* __restrict__ W_out, const float* __restrict__ emb,
    u16* __restrict__ encW, u16* __restrict__ decW, u16* __restrict__ woutW,
    u16* __restrict__ embB)
{
  const int total = ENC_TOT + DEC_TOT + WOUT_TOT + EMB_TOT;
  for (int idx = blockIdx.x*blockDim.x + threadIdx.x; idx < total; idx += gridDim.x*blockDim.x){
    if (idx < ENC_TOT){
      // [dir][cg(16)][gate(4)][kt(24)][nt(2)][512]
      int dir = idx / 1572864;
      int r0  = idx - dir*1572864;
      int cg  = r0 / 98304;  int r1 = r0 - cg*98304;
      int g   = r1 / 24576;  int r2 = r1 - g*24576;
      int kt  = r2 / 1024;   int r3 = r2 - kt*1024;
      int nt  = r3 >> 9;     int li = r3 & 511;
      int l = li >> 3, i = li & 7;
      int k   = kt*32 + ((l>>4)<<3) + i;
      int col = g*512 + cg*32 + nt*16 + (l&15);
      const float* Wih = dir ? Wih_b : Wih_f;
      const float* Whh = dir ? Whh_b : Whh_f;
      float v = (k < 256) ? Wih[col*256 + k] : Whh[col*512 + (k-256)];
      encW[idx] = f2b(v);
    } else if (idx < ENC_TOT + DEC_TOT){
      // [cg(32)][gate(4)][kt(28)][512]
      int id = idx - ENC_TOT;
      int cg = id / 57344;   int r1 = id - cg*57344;
      int g  = r1 / 14336;   int r2 = r1 - g*14336;
      int kt = r2 >> 9;      int li = r2 & 511;
      int l = li >> 3, i = li & 7;
      int k   = kt*32 + ((l>>4)<<3) + i;
      int col = g*512 + cg*16 + (l&15);
      float v = (k < 384) ? Wih_d[col*384 + k] : Whh_d[col*512 + (k-384)];
      decW[id] = f2b(v);
    } else if (idx < ENC_TOT + DEC_TOT + WOUT_TOT){
      // [w(4)][kt(16)][512]
      int id = idx - ENC_TOT - DEC_TOT;
      int w  = id >> 13;  int r1 = id & 8191;
      int kt = r1 >> 9;   int li = r1 & 511;
      int l = li >> 3, i = li & 7;
      int k  = kt*32 + ((l>>4)<<3) + i;
      int vv = w*16 + (l&15);
      woutW[id] = f2b(W_out[vv*512 + k]);
    } else {
      int id = idx - ENC_TOT - DEC_TOT - WOUT_TOT;
      embB[id] = f2b(emb[id]);
    }
  }
}

__global__ void prep_zero(int4* __restrict__ henc, unsigned* __restrict__ flg){
  const int n = (2*2*BB*HH*2)/16;
  int4 z = make_int4(0,0,0,0);
  const int gid = blockIdx.x*blockDim.x + threadIdx.x;
  const int stride = gridDim.x*blockDim.x;
  for (int i = gid; i < n; i += stride) henc[i] = z;
  for (int i = gid; i < 24*64; i += stride) flg[i] = 0u;
}

// ---------------- encoder: bidirectional LSTM, 128 steps, grid-resident ----------------
// grid 256: bg = bid&7 (batch group), dir = (bid>>3)&1, cg = bid>>4 (unit group of 32)
// sync: per-(dir,bg) group of 16 wgs via monotonic flags; h through IC (relaxed coherent)
__global__ __launch_bounds__(256, 1) void encoder_kernel(
    const int* __restrict__ xseq, const u16* __restrict__ embB,
    const float* __restrict__ b_f, const float* __restrict__ b_b,
    const u16* __restrict__ encW, u16* __restrict__ h_enc, unsigned* __restrict__ flg)
{
  __shared__ u16  sA[64*PITCH_E];
  __shared__ float sG[4*64*34];
  const int tid  = threadIdx.x;
  const int wave = tid >> 6, lane = tid & 63;
  const int bid  = blockIdx.x;
  const int bg   = bid & 7;
  const int dir  = (bid >> 3) & 1;
  const int cg   = bid >> 4;
  const int ml   = lane & 15;
  const int kh   = (lane >> 4) * 8;
  const int rowb = (lane >> 4) * 4;

  unsigned* gflags = flg + (dir*8 + bg)*64;
  unsigned* myflag = gflags + cg;

  // weights -> registers (once)
  bf16x8 wf[24][2];
  {
    const u16* wb = encW + (size_t)(((dir*16 + cg)*4 + wave)*48)*512 + lane*8;
    #pragma unroll
    for (int kt=0;kt<24;kt++)
      #pragma unroll
      for (int nt=0;nt<2;nt++)
        wf[kt][nt] = *(const bf16x8*)(wb + (kt*2+nt)*512);
  }
  const float* bias = dir ? b_b : b_f;
  float bval[2];
  #pragma unroll
  for (int nt=0;nt<2;nt++) bval[nt] = bias[wave*512 + cg*32 + nt*16 + ml];

  float c8[8];
  #pragma unroll
  for (int p=0;p<8;p++) c8[p] = 0.f;
  const int brow = bg*64 + lane;   // this thread's staged/elementwise row

  // pre-stage emb for t=0: thread (wave,lane) -> row lane, emb chunk wave (64 elems)
  {
    const int t_eff0 = dir ? (TT-1) : 0;
    const int xi = xseq[brow*TT + t_eff0];
    const int4* ep = (const int4*)(embB + xi*EE + wave*64);
    int4* dst = (int4*)&sA[lane*PITCH_E + wave*64];
    #pragma unroll
    for (int j=0;j<8;j++) dst[j] = ep[j];
  }

  #pragma unroll 1
  for (int t=0; t<TT; t++){
    const int cur = t & 1, nxt = cur ^ 1;
    // wait: h(t) ready (group flags >= t; trivially true at t=0)
    if (wave == 0 && lane < 16){
      while (__hip_atomic_load(gflags + lane, __ATOMIC_RELAXED, __HIP_MEMORY_SCOPE_AGENT) < (unsigned)t) { }
    }
    __syncthreads();
    // stage h: row lane, chunk wave (128 elems) -- coherent 8B loads from IC
    {
      const ull* hp = (const ull*)(h_enc + ((size_t)((dir*2 + cur)*BB) + brow)*HH + wave*128);
      int4* dsth = (int4*)&sA[lane*PITCH_E + 256 + wave*128];
      #pragma unroll
      for (int j=0;j<16;j++){
        P2 u2;
        u2.q[0] = cload(hp + 2*j);
        u2.q[1] = cload(hp + 2*j + 1);
        dsth[j] = u2.v;
      }
    }
    __syncthreads();
    // gate GEMM: [64 x 768] @ W[768 x 128]; wave = one gate's 32 units
    f32x4 acc[4][2];
    #pragma unroll
    for (int mt=0;mt<4;mt++)
      #pragma unroll
      for (int nt=0;nt<2;nt++)
        acc[mt][nt] = (f32x4){0.f,0.f,0.f,0.f};
    #pragma unroll
    for (int kt=0;kt<24;kt++){
      bf16x8 a[4];
      #pragma unroll
      for (int mt=0;mt<4;mt++)
        a[mt] = *(const bf16x8*)&sA[(mt*16 + ml)*PITCH_E + kt*32 + kh];
      #pragma unroll
      for (int mt=0;mt<4;mt++)
        #pragma unroll
        for (int nt=0;nt<2;nt++)
          acc[mt][nt] = __builtin_amdgcn_mfma_f32_16x16x32_bf16(a[mt], wf[kt][nt], acc[mt][nt], 0,0,0);
    }
    #pragma unroll
    for (int mt=0;mt<4;mt++)
      #pragma unroll
      for (int nt=0;nt<2;nt++)
        #pragma unroll
        for (int r=0;r<4;r++)
          sG[(wave*64 + mt*16 + rowb + r)*34 + nt*16 + ml] = acc[mt][nt][r] + bval[nt];
    __syncthreads();
    // elementwise: thread (wave,lane) -> row lane, units [wave*8, wave*8+8)
    {
      U8 u;
      #pragma unroll
      for (int p=0;p<8;p++){
        const int uu = wave*8 + p;
        float gi = sG[(      lane)*34 + uu];
        float gf = sG[( 64 + lane)*34 + uu];
        float gg = sG[(128 + lane)*34 + uu];
        float go = sG[(192 + lane)*34 + uu];
        float c = sigf(gf)*c8[p] + sigf(gi)*tanhc(gg);
        c8[p] = c;
        u.s[p] = f2b(sigf(go)*tanhc(c));
      }
      ull* hd = (ull*)(h_enc + ((size_t)((dir*2 + nxt)*BB) + brow)*HH + cg*32 + wave*8);
      cstore(hd, u.q[0]);
      cstore(hd + 1, u.q[1]);
    }
    __syncthreads();   // implies s_waitcnt vmcnt(0) per wave -> h stores at IC
    if (tid == 0)
      __hip_atomic_store(myflag, (unsigned)(t+1), __ATOMIC_RELAXED, __HIP_MEMORY_SCOPE_AGENT);
    // overlap: stage next step's embedding while group peers finish
    if (t+1 < TT){
      const int t_eff = dir ? (TT-2-t) : (t+1);
      const int xi = xseq[brow*TT + t_eff];
      const int4* ep = (const int4*)(embB + xi*EE + wave*64);
      int4* dst = (int4*)&sA[lane*PITCH_E + wave*64];
      #pragma unroll
      for (int j=0;j<8;j++) dst[j] = ep[j];
    }
  }
}

// ---------------- latent: mu/logvar/z/h0 ----------------
__global__ __launch_bounds__(256) void latent_kernel(
    const float* __restrict__ eps,
    const float* __restrict__ W_mu, const float* __restrict__ b_mu,
    const float* __restrict__ W_lv, const float* __restrict__ b_lv,
    const float* __restrict__ W_di, const float* __restrict__ b_di,
    const u16* __restrict__ h_enc, u16* __restrict__ h_dec0,
    u16* __restrict__ z_bf, float* __restrict__ outp)
{
  __shared__ float hc[16][1024];
  __shared__ float lvs[16][128];
  __shared__ float zs[16][128];
  const int tid = threadIdx.x;
  const int r0 = blockIdx.x * 16;
  for (int s = tid; s < 16*1024; s += 256){
    int r = s >> 10, k = s & 1023;
    float v = (k < 512)
      ? b2f(h_enc[(size_t)(r0 + r)*HH + k])                 // fwd final (dir0 buf0)
      : b2f(h_enc[(size_t)(2*BB + r0 + r)*HH + (k - 512)]); // bwd final (dir1 buf0)
    hc[r][k] = v;
  }
  __syncthreads();
  float acc[16];
  #pragma unroll
  for (int r=0;r<16;r++) acc[r] = 0.f;
  const float* wrow = (tid < 128) ? (W_mu + (size_t)tid*1024) : (W_lv + (size_t)(tid-128)*1024);
  for (int k=0;k<1024;k++){
    float w = wrow[k];
    #pragma unroll
    for (int r=0;r<16;r++) acc[r] += w * hc[r][k];
  }
  const float bb_ = (tid < 128) ? b_mu[tid] : b_lv[tid-128];
  if (tid >= 128){
    const int j = tid - 128;
    #pragma unroll
    for (int r=0;r<16;r++){
      float lv = acc[r] + bb_;
      outp[4259840u + (size_t)(r0+r)*LL + j] = lv;
      lvs[r][j] = lv;
    }
  }
  __syncthreads();
  if (tid < 128){
    const int j = tid;
    #pragma unroll
    for (int r=0;r<16;r++){
      float mu = acc[r] + bb_;
      outp[4194304u + (size_t)(r0+r)*LL + j] = mu;
      float z = mu + eps[(size_t)(r0+r)*LL + j] * __expf(0.5f * lvs[r][j]);
      zs[r][j] = z;
      z_bf[(size_t)(r0+r)*LL + j] = f2b(z);
    }
  }
  __syncthreads();
  float a1[16], a2[16];
  #pragma unroll
  for (int r=0;r<16;r++){ a1[r]=0.f; a2[r]=0.f; }
  const float* w1 = W_di + (size_t)tid*LL;
  const float* w2 = W_di + (size_t)(tid+256)*LL;
  for (int k=0;k<LL;k++){
    float x1 = w1[k], x2 = w2[k];
    #pragma unroll
    for (int r=0;r<16;r++){ a1[r] += x1*zs[r][k]; a2[r] += x2*zs[r][k]; }
  }
  const float bd1 = b_di[tid], bd2 = b_di[tid+256];
  #pragma unroll
  for (int r=0;r<16;r++){
    h_dec0[(size_t)(r0+r)*HH + tid]       = f2b(a1[r] + bd1);
    h_dec0[(size_t)(r0+r)*HH + tid + 256] = f2b(a2[r] + bd2);
  }
}

// ---------------- decoder LSTM, 128 steps, writes hs ----------------
// grid 256: bg = bid&7, cg = bid>>3 (unit group of 16); sync per-bg group of 32 wgs
__global__ __launch_bounds__(256, 1) void decoder_kernel(
    const int* __restrict__ tseq, const u16* __restrict__ embB,
    const float* __restrict__ b_d, const u16* __restrict__ decW,
    const u16* __restrict__ z_bf, u16* __restrict__ h_dec,
    u16* __restrict__ hs, unsigned* __restrict__ flg)
{
  __shared__ u16  sA[64*PITCH_D];
  __shared__ float sG[4*64*18];
  const int tid  = threadIdx.x;
  const int wave = tid >> 6, lane = tid & 63;
  const int bid  = blockIdx.x;
  const int bg   = bid & 7;
  const int cg   = bid >> 3;
  const int ml   = lane & 15;
  const int kh   = (lane >> 4) * 8;
  const int rowb = (lane >> 4) * 4;

  unsigned* gflags = flg + bg*64;
  unsigned* myflag = gflags + cg;

  bf16x8 wf[28];
  {
    const u16* wb = decW + (size_t)((cg*4 + wave)*28)*512 + lane*8;
    #pragma unroll
    for (int kt=0;kt<28;kt++)
      wf[kt] = *(const bf16x8*)(wb + kt*512);
  }
  const float bval = b_d[wave*512 + cg*16 + ml];
  float c4[4];
  #pragma unroll
  for (int p=0;p<4;p++) c4[p] = 0.f;
  const int brow = bg*64 + lane;

  // stage z once (constant over t): row lane, chunk wave (32 elems)
  {
    const int4* zp = (const int4*)(z_bf + brow*LL + wave*32);
    int4* dstz = (int4*)&sA[lane*PITCH_D + 256 + wave*32];
    #pragma unroll
    for (int j=0;j<4;j++) dstz[j] = zp[j];
  }
  // pre-stage emb for t=0
  {
    const int xi = tseq[brow*TT + 0];
    const int4* ep = (const int4*)(embB + xi*EE + wave*64);
    int4* dst = (int4*)&sA[lane*PITCH_D + wave*64];
    #pragma unroll
    for (int j=0;j<8;j++) dst[j] = ep[j];
  }

  #pragma unroll 1
  for (int t=0; t<TT; t++){
    const int cur = t & 1, nxt = cur ^ 1;
    if (wave == 0 && lane < 32){
      while (__hip_atomic_load(gflags + lane, __ATOMIC_RELAXED, __HIP_MEMORY_SCOPE_AGENT) < (unsigned)t) { }
    }
    __syncthreads();
    // stage h: row lane, chunk wave (128 elems) -- coherent 8B loads from IC
    {
      const ull* hp = (const ull*)(h_dec + ((size_t)(cur*BB) + brow)*HH + wave*128);
      int4* dsth = (int4*)&sA[lane*PITCH_D + 384 + wave*128];
      #pragma unroll
      for (int j=0;j<16;j++){
        P2 u2;
        u2.q[0] = cload(hp + 2*j);
        u2.q[1] = cload(hp + 2*j + 1);
        dsth[j] = u2.v;
      }
    }
    __syncthreads();
    f32x4 acc[4];
    #pragma unroll
    for (int mt=0;mt<4;mt++) acc[mt] = (f32x4){0.f,0.f,0.f,0.f};
    #pragma unroll
    for (int kt=0;kt<28;kt++){
      bf16x8 a[4];
      #pragma unroll
      for (int mt=0;mt<4;mt++)
        a[mt] = *(const bf16x8*)&sA[(mt*16 + ml)*PITCH_D + kt*32 + kh];
      #pragma unroll
      for (int mt=0;mt<4;mt++)
        acc[mt] = __builtin_amdgcn_mfma_f32_16x16x32_bf16(a[mt], wf[kt], acc[mt], 0,0,0);
    }
    #pragma unroll
    for (int mt=0;mt<4;mt++)
      #pragma unroll
      for (int r=0;r<4;r++)
        sG[(wave*64 + mt*16 + rowb + r)*18 + ml] = acc[mt][r] + bval;
    __syncthreads();
    // elementwise: row lane, units [wave*4, wave*4+4)
    {
      U4 u;
      #pragma unroll
      for (int p=0;p<4;p++){
        const int uu = wave*4 + p;
        float gi = sG[(      lane)*18 + uu];
        float gf = sG[( 64 + lane)*18 + uu];
        float gg = sG[(128 + lane)*18 + uu];
        float go = sG[(192 + lane)*18 + uu];
        float c = sigf(gf)*c4[p] + sigf(gi)*tanhc(gg);
        c4[p] = c;
        u.s[p] = f2b(sigf(go)*tanhc(c));
      }
      ull* hd1 = (ull*)(h_dec + ((size_t)(nxt*BB) + brow)*HH + cg*16 + wave*4);
      cstore(hd1, u.q);
      u16* hd2 = hs + ((size_t)t*BB + brow)*HH + cg*16 + wave*4;  // normal cached store
      *(int2*)hd2 = u.v;
    }
    __syncthreads();   // implies s_waitcnt vmcnt(0) per wave -> h stores at IC
    if (tid == 0)
      __hip_atomic_store(myflag, (unsigned)(t+1), __ATOMIC_RELAXED, __HIP_MEMORY_SCOPE_AGENT);
    if (t+1 < TT){
      const int xi = tseq[brow*TT + (t+1)];
      const int4* ep = (const int4*)(embB + xi*EE + wave*64);
      int4* dst = (int4*)&sA[lane*PITCH_D + wave*64];
      #pragma unroll
      for (int j=0;j<8;j++) dst[j] = ep[j];
    }
  }
}

// ---------------- recon: [65536,512] @ W_out^T[512,64] + b_out ----------------
__global__ __launch_bounds__(256) void recon_kernel(
    const u16* __restrict__ hs, const u16* __restrict__ woutW,
    const float* __restrict__ b_out, float* __restrict__ outp)
{
  __shared__ u16 sA[64*PITCH_R];
  const int tid  = threadIdx.x;
  const int wave = tid >> 6, lane = tid & 63;
  const int row0 = blockIdx.x * 64;
  const int ml = lane & 15;
  const int kh = (lane >> 4) * 8;
  {
    // row lane, chunk wave (128 elems)
    const int4* hp = (const int4*)(hs + (size_t)(row0 + lane)*HH + wave*128);
    int4* dst = (int4*)&sA[lane*PITCH_R + wave*128];
    #pragma unroll
    for (int j=0;j<16;j++) dst[j] = hp[j];
  }
  bf16x8 wf[16];
  #pragma unroll
  for (int kt=0;kt<16;kt++)
    wf[kt] = *(const bf16x8*)(woutW + ((wave*16 + kt) << 9) + lane*8);
  __syncthreads();
  f32x4 acc[4];
  #pragma unroll
  for (int mt=0;mt<4;mt++) acc[mt] = (f32x4){0.f,0.f,0.f,0.f};
  #pragma unroll
  for (int kt=0;kt<16;kt++){
    #pragma unroll
    for (int mt=0;mt<4;mt++){
      bf16x8 a = *(const bf16x8*)&sA[(mt*16 + ml)*PITCH_R + kt*32 + kh];
      acc[mt] = __builtin_amdgcn_mfma_f32_16x16x32_bf16(a, wf[kt], acc[mt], 0,0,0);
    }
  }
  const float bo = b_out[wave*16 + ml];
  #pragma unroll
  for (int mt=0;mt<4;mt++)
    #pragma unroll
    for (int r=0;r<4;r++){
      int fr = row0 + mt*16 + ((lane>>4)<<2) + r;  // flat row = t*512 + b
      int tt = fr >> 9, b = fr & 511;
      outp[(size_t)(b*TT + tt)*VV + wave*16 + ml] = acc[mt][r] + bo;
    }
}

extern "C" void kernel_launch(void* const* d_in, const int* in_sizes, int n_in,
                              void* d_out, int out_size, void* d_ws, size_t ws_size,
                              hipStream_t stream)
{
  (void)in_sizes; (void)n_in; (void)out_size; (void)ws_size;
  const int*   x     = (const int*)d_in[0];
  const int*   tgt   = (const int*)d_in[1];
  const float* eps   = (const float*)d_in[2];
  const float* emb   = (const float*)d_in[3];
  const float* Wih_f = (const float*)d_in[4];
  const float* Whh_f = (const float*)d_in[5];
  const float* b_f   = (const float*)d_in[6];
  const float* Wih_b = (const float*)d_in[7];
  const float* Whh_b = (const float*)d_in[8];
  const float* b_b   = (const float*)d_in[9];
  const float* W_mu  = (const float*)d_in[10];
  const float* b_mu  = (const float*)d_in[11];
  const float* W_lv  = (const float*)d_in[12];
  const float* b_lv  = (const float*)d_in[13];
  const float* W_di  = (const float*)d_in[14];
  const float* b_di  = (const float*)d_in[15];
  const float* Wih_d = (const float*)d_in[16];
  const float* Whh_d = (const float*)d_in[17];
  const float* b_d   = (const float*)d_in[18];
  const float* W_out = (const float*)d_in[19];
  const float* b_out = (const float*)d_in[20];

  char* ws = (char*)d_ws;
  u16* encW  = (u16*)(ws + OFF_ENCW);
  u16* decW  = (u16*)(ws + OFF_DECW);
  u16* woutW = (u16*)(ws + OFF_WOUT);
  u16* embB  = (u16*)(ws + OFF_EMBB);
  u16* henc  = (u16*)(ws + OFF_HENC);
  u16* hdec  = (u16*)(ws + OFF_HDEC);
  u16* zbf   = (u16*)(ws + OFF_ZBF);
  u16* hsbuf = (u16*)(ws + OFF_HS);
  unsigned* flg = (unsigned*)(ws + OFF_FLG);
  float* outp = (float*)d_out;

  prep_weights<<<2048, 256, 0, stream>>>(Wih_f, Whh_f, Wih_b, Whh_b, Wih_d, Whh_d, W_out, emb,
                                         encW, decW, woutW, embB);
  prep_zero<<<256, 256, 0, stream>>>((int4*)henc, flg);
  encoder_kernel<<<256, 256, 0, stream>>>(x, embB, b_f, b_b, encW, henc, flg);
  latent_kernel<<<32, 256, 0, stream>>>(eps, W_mu, b_mu, W_lv, b_lv, W_di, b_di,
                                        henc, hdec, zbf, outp);
  decoder_kernel<<<256, 256, 0, stream>>>(tgt, embB, b_d, decW, zbf, hdec, hsbuf, flg + 16*64);
  recon_kernel<<<1024, 256, 0, stream>>>(hsbuf, woutW, b_out, outp);
}

// Round 5
// 1781.934 us; speedup vs baseline: 4.0777x; 2.0084x over previous
//
#include <hip/hip_runtime.h>

#define BB 512
#define TT 128
#define VV 64
#define EE 256
#define HH 512
#define LL 128

typedef __bf16 bf16x8 __attribute__((ext_vector_type(8)));
typedef float f32x4 __attribute__((ext_vector_type(4)));
typedef unsigned short u16;
typedef unsigned long long ull;

#define PITCH_E 792   // 768+24 elems; 1584B/row, 8B aligned
#define PITCH_D 920   // 896+24; 1840B/row
#define PITCH_R 536   // 512+24

// ---- workspace layout (bytes) ----
#define ENC_TOT  3145728   // enc weight frag elems (2 dirs x 768x2048)
#define DEC_TOT  1835008   // dec weight frag elems (896x2048)
#define WOUT_TOT 32768     // W_out frag elems (512x64)
#define EMB_TOT  16384     // emb bf16 elems
#define OFF_ENCW 0ull
#define OFF_DECW 6291456ull
#define OFF_WOUT 9961472ull
#define OFF_EMBB 10027008ull
#define OFF_HENC 10059776ull   // [2dir][2buf][512][512] bf16
#define OFF_HDEC 12156928ull   // [2buf][512][512] bf16
#define OFF_ZBF  13205504ull   // [512][128] bf16
#define OFF_HS   13336576ull   // [128][512][512] bf16
#define OFF_FLG  80445440ull   // [24][64] u32 flags (enc groups 0..15, dec 16..23)

__device__ __forceinline__ float b2f(u16 b){
  unsigned int u = ((unsigned int)b) << 16;
  return __builtin_bit_cast(float, u);
}
__device__ __forceinline__ u16 f2b(float x){
  unsigned int u = __builtin_bit_cast(unsigned int, x);
  unsigned int lsb = (u >> 16) & 1u;
  u += 0x7fffu + lsb;
  return (u16)(u >> 16);
}
__device__ __forceinline__ float sigf(float x){ return 1.0f/(1.0f + __expf(-x)); }
__device__ __forceinline__ float tanhc(float x){
  x = fminf(15.0f, fmaxf(-15.0f, x));
  float e = __expf(2.0f*x);
  return (e - 1.0f) / (e + 1.0f);
}

// relaxed agent-scope coherent access (sc0 sc1; bypass L1/L2 -> IC; NO wbl2/inv)
__device__ __forceinline__ ull cload(const ull* p){
  return __hip_atomic_load(p, __ATOMIC_RELAXED, __HIP_MEMORY_SCOPE_AGENT);
}
__device__ __forceinline__ void cstore(ull* p, ull v){
  __hip_atomic_store(p, v, __ATOMIC_RELAXED, __HIP_MEMORY_SCOPE_AGENT);
}

union U8 { u16 s[8]; int4 v; ull q[2]; };
union U4 { u16 s[4]; int2 v; ull q; };

// ---------------- prep: weights -> bf16 MFMA B-fragment order; emb -> bf16 ----------------
__global__ void prep_weights(
    const float* __restrict__ Wih_f, const float* __restrict__ Whh_f,
    const float* __restrict__ Wih_b, const float* __restrict__ Whh_b,
    const float* __restrict__ Wih_d, const float* __restrict__ Whh_d,
    const float* __restrict__ W_out, const float* __restrict__ emb,
    u16* __restrict__ encW, u16* __restrict__ decW, u16* __restrict__ woutW,
    u16* __restrict__ embB)
{
  const int total = ENC_TOT + DEC_TOT + WOUT_TOT + EMB_TOT;
  for (int idx = blockIdx.x*blockDim.x + threadIdx.x; idx < total; idx += gridDim.x*blockDim.x){
    if (idx < ENC_TOT){
      // [dir][cg(16)][gate(4)][kt(24)][nt(2)][512]
      int dir = idx / 1572864;
      int r0  = idx - dir*1572864;
      int cg  = r0 / 98304;  int r1 = r0 - cg*98304;
      int g   = r1 / 24576;  int r2 = r1 - g*24576;
      int kt  = r2 / 1024;   int r3 = r2 - kt*1024;
      int nt  = r3 >> 9;     int li = r3 & 511;
      int l = li >> 3, i = li & 7;
      int k   = kt*32 + ((l>>4)<<3) + i;
      int col = g*512 + cg*32 + nt*16 + (l&15);
      const float* Wih = dir ? Wih_b : Wih_f;
      const float* Whh = dir ? Whh_b : Whh_f;
      float v = (k < 256) ? Wih[col*256 + k] : Whh[col*512 + (k-256)];
      encW[idx] = f2b(v);
    } else if (idx < ENC_TOT + DEC_TOT){
      // [cg(32)][gate(4)][kt(28)][512]
      int id = idx - ENC_TOT;
      int cg = id / 57344;   int r1 = id - cg*57344;
      int g  = r1 / 14336;   int r2 = r1 - g*14336;
      int kt = r2 >> 9;      int li = r2 & 511;
      int l = li >> 3, i = li & 7;
      int k   = kt*32 + ((l>>4)<<3) + i;
      int col = g*512 + cg*16 + (l&15);
      float v = (k < 384) ? Wih_d[col*384 + k] : Whh_d[col*512 + (k-384)];
      decW[id] = f2b(v);
    } else if (idx < ENC_TOT + DEC_TOT + WOUT_TOT){
      // [w(4)][kt(16)][512]
      int id = idx - ENC_TOT - DEC_TOT;
      int w  = id >> 13;  int r1 = id & 8191;
      int kt = r1 >> 9;   int li = r1 & 511;
      int l = li >> 3, i = li & 7;
      int k  = kt*32 + ((l>>4)<<3) + i;
      int vv = w*16 + (l&15);
      woutW[id] = f2b(W_out[vv*512 + k]);
    } else {
      int id = idx - ENC_TOT - DEC_TOT - WOUT_TOT;
      embB[id] = f2b(emb[id]);
    }
  }
}

__global__ void prep_zero(int4* __restrict__ henc, unsigned* __restrict__ flg){
  const int n = (2*2*BB*HH*2)/16;
  int4 z = make_int4(0,0,0,0);
  const int gid = blockIdx.x*blockDim.x + threadIdx.x;
  const int stride = gridDim.x*blockDim.x;
  for (int i = gid; i < n; i += stride) henc[i] = z;
  for (int i = gid; i < 24*64; i += stride) flg[i] = 0u;
}

// ---------------- encoder: bidirectional LSTM, 128 steps, grid-resident ----------------
// grid 256: bg = bid&7, dir = (bid>>3)&1, cg = bid>>4 (unit group of 32)
// sync: per-(dir,bg) group of 16 wgs; h through IC with COALESCED coherent ops
__global__ __launch_bounds__(256, 1) void encoder_kernel(
    const int* __restrict__ xseq, const u16* __restrict__ embB,
    const float* __restrict__ b_f, const float* __restrict__ b_b,
    const u16* __restrict__ encW, u16* __restrict__ h_enc, unsigned* __restrict__ flg)
{
  __shared__ u16  sA[64*PITCH_E];
  __shared__ float sG[4*64*34];
  const int tid  = threadIdx.x;
  const int wave = tid >> 6, lane = tid & 63;
  const int bid  = blockIdx.x;
  const int bg   = bid & 7;
  const int dir  = (bid >> 3) & 1;
  const int cg   = bid >> 4;
  const int ml   = lane & 15;
  const int kh   = (lane >> 4) * 8;
  const int rowb = (lane >> 4) * 4;

  unsigned* gflags = flg + (dir*8 + bg)*64;
  unsigned* myflag = gflags + cg;

  // weights -> registers (once)
  bf16x8 wf[24][2];
  {
    const u16* wb = encW + (size_t)(((dir*16 + cg)*4 + wave)*48)*512 + lane*8;
    #pragma unroll
    for (int kt=0;kt<24;kt++)
      #pragma unroll
      for (int nt=0;nt<2;nt++)
        wf[kt][nt] = *(const bf16x8*)(wb + (kt*2+nt)*512);
  }
  const float* bias = dir ? b_b : b_f;
  float bval[2];
  #pragma unroll
  for (int nt=0;nt<2;nt++) bval[nt] = bias[wave*512 + cg*32 + nt*16 + ml];

  // cell ownership (coalesced full-line stores): piece p = tid + 256*j, j in {0,1}
  // row = p>>3, sub8B = p&7 (4 units each)
  const int rc = tid >> 3, sc = tid & 7;
  float cst[2][4];
  #pragma unroll
  for (int j=0;j<2;j++)
    #pragma unroll
    for (int i=0;i<4;i++) cst[j][i] = 0.f;
  const int brow = bg*64 + lane;

  // pre-stage emb for t=0: row lane, emb chunk wave (64 elems)
  {
    const int t_eff0 = dir ? (TT-1) : 0;
    const int xi = xseq[brow*TT + t_eff0];
    const int4* ep = (const int4*)(embB + xi*EE + wave*64);
    int4* dst = (int4*)&sA[lane*PITCH_E + wave*64];
    #pragma unroll
    for (int j=0;j<8;j++) dst[j] = ep[j];
  }

  #pragma unroll 1
  for (int t=0; t<TT; t++){
    const int cur = t & 1, nxt = cur ^ 1;
    // wait: h(t) ready (group flags >= t; trivially true at t=0)
    if (wave == 0 && lane < 16){
      while (__hip_atomic_load(gflags + lane, __ATOMIC_RELAXED, __HIP_MEMORY_SCOPE_AGENT) < (unsigned)t) { }
    }
    __syncthreads();
    // stage h: COALESCED coherent 8B loads of the contiguous 64KB slab
    // piece p = tid + 256*j -> row = p>>7 (128 ull/row), col8 = p&127
    {
      const ull* hs8 = (const ull*)(h_enc + ((size_t)((dir*2 + cur)*BB) + bg*64)*HH);
      ull q[32];
      #pragma unroll
      for (int j=0;j<32;j++) q[j] = cload(hs8 + tid + 256*j);
      #pragma unroll
      for (int j=0;j<32;j++){
        const int p = tid + 256*j;
        *(ull*)&sA[(p>>7)*PITCH_E + 256 + (p&127)*4] = q[j];
      }
    }
    __syncthreads();
    // gate GEMM: [64 x 768] @ W[768 x 128]; wave = one gate's 32 units
    f32x4 acc[4][2];
    #pragma unroll
    for (int mt=0;mt<4;mt++)
      #pragma unroll
      for (int nt=0;nt<2;nt++)
        acc[mt][nt] = (f32x4){0.f,0.f,0.f,0.f};
    #pragma unroll
    for (int kt=0;kt<24;kt++){
      bf16x8 a[4];
      #pragma unroll
      for (int mt=0;mt<4;mt++)
        a[mt] = *(const bf16x8*)&sA[(mt*16 + ml)*PITCH_E + kt*32 + kh];
      #pragma unroll
      for (int mt=0;mt<4;mt++)
        #pragma unroll
        for (int nt=0;nt<2;nt++)
          acc[mt][nt] = __builtin_amdgcn_mfma_f32_16x16x32_bf16(a[mt], wf[kt][nt], acc[mt][nt], 0,0,0);
    }
    #pragma unroll
    for (int mt=0;mt<4;mt++)
      #pragma unroll
      for (int nt=0;nt<2;nt++)
        #pragma unroll
        for (int r=0;r<4;r++)
          sG[(wave*64 + mt*16 + rowb + r)*34 + nt*16 + ml] = acc[mt][nt][r] + bval[nt];
    __syncthreads();
    // elementwise cell + FULL-LINE coalesced coherent stores
    // thread: rows rc and rc+32, local units sc*4..sc*4+4
    {
      ull* hd = (ull*)(h_enc + ((size_t)((dir*2 + nxt)*BB) + bg*64)*HH);
      #pragma unroll
      for (int j=0;j<2;j++){
        const int rr = rc + 32*j;
        U4 u;
        #pragma unroll
        for (int i=0;i<4;i++){
          const int uu = sc*4 + i;
          float gi = sG[(      rr)*34 + uu];
          float gf = sG[( 64 + rr)*34 + uu];
          float gg = sG[(128 + rr)*34 + uu];
          float go = sG[(192 + rr)*34 + uu];
          float c = sigf(gf)*cst[j][i] + sigf(gi)*tanhc(gg);
          cst[j][i] = c;
          u.s[i] = f2b(sigf(go)*tanhc(c));
        }
        cstore(hd + (rr*128 + cg*8 + sc), u.q);
      }
    }
    __syncthreads();   // drains vmcnt(0) per wave -> h stores at IC
    if (tid == 0)
      __hip_atomic_store(myflag, (unsigned)(t+1), __ATOMIC_RELAXED, __HIP_MEMORY_SCOPE_AGENT);
    // overlap: stage next step's embedding while group peers finish
    if (t+1 < TT){
      const int t_eff = dir ? (TT-2-t) : (t+1);
      const int xi = xseq[brow*TT + t_eff];
      const int4* ep = (const int4*)(embB + xi*EE + wave*64);
      int4* dst = (int4*)&sA[lane*PITCH_E + wave*64];
      #pragma unroll
      for (int j=0;j<8;j++) dst[j] = ep[j];
    }
  }
}

// ---------------- latent: mu/logvar/z/h0 ----------------
__global__ __launch_bounds__(256) void latent_kernel(
    const float* __restrict__ eps,
    const float* __restrict__ W_mu, const float* __restrict__ b_mu,
    const float* __restrict__ W_lv, const float* __restrict__ b_lv,
    const float* __restrict__ W_di, const float* __restrict__ b_di,
    const u16* __restrict__ h_enc, u16* __restrict__ h_dec0,
    u16* __restrict__ z_bf, float* __restrict__ outp)
{
  __shared__ float hc[16][1024];
  __shared__ float lvs[16][128];
  __shared__ float zs[16][128];
  const int tid = threadIdx.x;
  const int r0 = blockIdx.x * 16;
  for (int s = tid; s < 16*1024; s += 256){
    int r = s >> 10, k = s & 1023;
    float v = (k < 512)
      ? b2f(h_enc[(size_t)(r0 + r)*HH + k])                 // fwd final (dir0 buf0)
      : b2f(h_enc[(size_t)(2*BB + r0 + r)*HH + (k - 512)]); // bwd final (dir1 buf0)
    hc[r][k] = v;
  }
  __syncthreads();
  float acc[16];
  #pragma unroll
  for (int r=0;r<16;r++) acc[r] = 0.f;
  const float* wrow = (tid < 128) ? (W_mu + (size_t)tid*1024) : (W_lv + (size_t)(tid-128)*1024);
  for (int k=0;k<1024;k++){
    float w = wrow[k];
    #pragma unroll
    for (int r=0;r<16;r++) acc[r] += w * hc[r][k];
  }
  const float bb_ = (tid < 128) ? b_mu[tid] : b_lv[tid-128];
  if (tid >= 128){
    const int j = tid - 128;
    #pragma unroll
    for (int r=0;r<16;r++){
      float lv = acc[r] + bb_;
      outp[4259840u + (size_t)(r0+r)*LL + j] = lv;
      lvs[r][j] = lv;
    }
  }
  __syncthreads();
  if (tid < 128){
    const int j = tid;
    #pragma unroll
    for (int r=0;r<16;r++){
      float mu = acc[r] + bb_;
      outp[4194304u + (size_t)(r0+r)*LL + j] = mu;
      float z = mu + eps[(size_t)(r0+r)*LL + j] * __expf(0.5f * lvs[r][j]);
      zs[r][j] = z;
      z_bf[(size_t)(r0+r)*LL + j] = f2b(z);
    }
  }
  __syncthreads();
  float a1[16], a2[16];
  #pragma unroll
  for (int r=0;r<16;r++){ a1[r]=0.f; a2[r]=0.f; }
  const float* w1 = W_di + (size_t)tid*LL;
  const float* w2 = W_di + (size_t)(tid+256)*LL;
  for (int k=0;k<LL;k++){
    float x1 = w1[k], x2 = w2[k];
    #pragma unroll
    for (int r=0;r<16;r++){ a1[r] += x1*zs[r][k]; a2[r] += x2*zs[r][k]; }
  }
  const float bd1 = b_di[tid], bd2 = b_di[tid+256];
  #pragma unroll
  for (int r=0;r<16;r++){
    h_dec0[(size_t)(r0+r)*HH + tid]       = f2b(a1[r] + bd1);
    h_dec0[(size_t)(r0+r)*HH + tid + 256] = f2b(a2[r] + bd2);
  }
}

// ---------------- decoder LSTM, 128 steps, writes hs ----------------
// grid 256: bg = bid&7, cg = bid>>3 (unit group of 16); sync per-bg group of 32 wgs
__global__ __launch_bounds__(256, 1) void decoder_kernel(
    const int* __restrict__ tseq, const u16* __restrict__ embB,
    const float* __restrict__ b_d, const u16* __restrict__ decW,
    const u16* __restrict__ z_bf, u16* __restrict__ h_dec,
    u16* __restrict__ hs, unsigned* __restrict__ flg)
{
  __shared__ u16  sA[64*PITCH_D];
  __shared__ float sG[4*64*18];
  const int tid  = threadIdx.x;
  const int wave = tid >> 6, lane = tid & 63;
  const int bid  = blockIdx.x;
  const int bg   = bid & 7;
  const int cg   = bid >> 3;
  const int ml   = lane & 15;
  const int kh   = (lane >> 4) * 8;
  const int rowb = (lane >> 4) * 4;

  unsigned* gflags = flg + bg*64;
  unsigned* myflag = gflags + cg;

  bf16x8 wf[28];
  {
    const u16* wb = decW + (size_t)((cg*4 + wave)*28)*512 + lane*8;
    #pragma unroll
    for (int kt=0;kt<28;kt++)
      wf[kt] = *(const bf16x8*)(wb + kt*512);
  }
  const float bval = b_d[wave*512 + cg*16 + ml];
  // cell ownership: piece = tid -> row = tid>>2, sub8B = tid&3 (4 units)
  const int rc = tid >> 2, sc = tid & 3;
  float cst[4];
  #pragma unroll
  for (int p=0;p<4;p++) cst[p] = 0.f;
  const int brow = bg*64 + lane;

  // stage z once (constant over t): row lane, chunk wave (32 elems)
  {
    const int4* zp = (const int4*)(z_bf + brow*LL + wave*32);
    int4* dstz = (int4*)&sA[lane*PITCH_D + 256 + wave*32];
    #pragma unroll
    for (int j=0;j<4;j++) dstz[j] = zp[j];
  }
  // pre-stage emb for t=0
  {
    const int xi = tseq[brow*TT + 0];
    const int4* ep = (const int4*)(embB + xi*EE + wave*64);
    int4* dst = (int4*)&sA[lane*PITCH_D + wave*64];
    #pragma unroll
    for (int j=0;j<8;j++) dst[j] = ep[j];
  }

  #pragma unroll 1
  for (int t=0; t<TT; t++){
    const int cur = t & 1, nxt = cur ^ 1;
    if (wave == 0 && lane < 32){
      while (__hip_atomic_load(gflags + lane, __ATOMIC_RELAXED, __HIP_MEMORY_SCOPE_AGENT) < (unsigned)t) { }
    }
    __syncthreads();
    // stage h: COALESCED coherent 8B loads of the contiguous 64KB slab
    {
      const ull* hs8 = (const ull*)(h_dec + ((size_t)(cur*BB) + bg*64)*HH);
      ull q[32];
      #pragma unroll
      for (int j=0;j<32;j++) q[j] = cload(hs8 + tid + 256*j);
      #pragma unroll
      for (int j=0;j<32;j++){
        const int p = tid + 256*j;
        *(ull*)&sA[(p>>7)*PITCH_D + 384 + (p&127)*4] = q[j];
      }
    }
    __syncthreads();
    f32x4 acc[4];
    #pragma unroll
    for (int mt=0;mt<4;mt++) acc[mt] = (f32x4){0.f,0.f,0.f,0.f};
    #pragma unroll
    for (int kt=0;kt<28;kt++){
      bf16x8 a[4];
      #pragma unroll
      for (int mt=0;mt<4;mt++)
        a[mt] = *(const bf16x8*)&sA[(mt*16 + ml)*PITCH_D + kt*32 + kh];
      #pragma unroll
      for (int mt=0;mt<4;mt++)
        acc[mt] = __builtin_amdgcn_mfma_f32_16x16x32_bf16(a[mt], wf[kt], acc[mt], 0,0,0);
    }
    #pragma unroll
    for (int mt=0;mt<4;mt++)
      #pragma unroll
      for (int r=0;r<4;r++)
        sG[(wave*64 + mt*16 + rowb + r)*18 + ml] = acc[mt][r] + bval;
    __syncthreads();
    // elementwise cell + coalesced stores (h coherent, hs plain)
    {
      U4 u;
      #pragma unroll
      for (int i=0;i<4;i++){
        const int uu = sc*4 + i;
        float gi = sG[(      rc)*18 + uu];
        float gf = sG[( 64 + rc)*18 + uu];
        float gg = sG[(128 + rc)*18 + uu];
        float go = sG[(192 + rc)*18 + uu];
        float c = sigf(gf)*cst[i] + sigf(gi)*tanhc(gg);
        cst[i] = c;
        u.s[i] = f2b(sigf(go)*tanhc(c));
      }
      ull* hd1 = (ull*)(h_dec + ((size_t)(nxt*BB) + bg*64)*HH);
      cstore(hd1 + (rc*128 + cg*4 + sc), u.q);
      ull* hd2 = (ull*)(hs + ((size_t)t*BB + bg*64)*HH);
      *(hd2 + rc*128 + cg*4 + sc) = u.q;   // normal cached store
    }
    __syncthreads();
    if (tid == 0)
      __hip_atomic_store(myflag, (unsigned)(t+1), __ATOMIC_RELAXED, __HIP_MEMORY_SCOPE_AGENT);
    if (t+1 < TT){
      const int xi = tseq[brow*TT + (t+1)];
      const int4* ep = (const int4*)(embB + xi*EE + wave*64);
      int4* dst = (int4*)&sA[lane*PITCH_D + wave*64];
      #pragma unroll
      for (int j=0;j<8;j++) dst[j] = ep[j];
    }
  }
}

// ---------------- recon: [65536,512] @ W_out^T[512,64] + b_out ----------------
__global__ __launch_bounds__(256) void recon_kernel(
    const u16* __restrict__ hs, const u16* __restrict__ woutW,
    const float* __restrict__ b_out, float* __restrict__ outp)
{
  __shared__ u16 sA[64*PITCH_R];
  const int tid  = threadIdx.x;
  const int wave = tid >> 6, lane = tid & 63;
  const int row0 = blockIdx.x * 64;
  const int ml = lane & 15;
  const int kh = (lane >> 4) * 8;
  {
    // row lane, chunk wave (128 elems)
    const int4* hp = (const int4*)(hs + (size_t)(row0 + lane)*HH + wave*128);
    int4* dst = (int4*)&sA[lane*PITCH_R + wave*128];
    #pragma unroll
    for (int j=0;j<16;j++) dst[j] = hp[j];
  }
  bf16x8 wf[16];
  #pragma unroll
  for (int kt=0;kt<16;kt++)
    wf[kt] = *(const bf16x8*)(woutW + ((wave*16 + kt) << 9) + lane*8);
  __syncthreads();
  f32x4 acc[4];
  #pragma unroll
  for (int mt=0;mt<4;mt++) acc[mt] = (f32x4){0.f,0.f,0.f,0.f};
  #pragma unroll
  for (int kt=0;kt<16;kt++){
    #pragma unroll
    for (int mt=0;mt<4;mt++){
      bf16x8 a = *(const bf16x8*)&sA[(mt*16 + ml)*PITCH_R + kt*32 + kh];
      acc[mt] = __builtin_amdgcn_mfma_f32_16x16x32_bf16(a, wf[kt], acc[mt], 0,0,0);
    }
  }
  const float bo = b_out[wave*16 + ml];
  #pragma unroll
  for (int mt=0;mt<4;mt++)
    #pragma unroll
    for (int r=0;r<4;r++){
      int fr = row0 + mt*16 + ((lane>>4)<<2) + r;  // flat row = t*512 + b
      int tt = fr >> 9, b = fr & 511;
      outp[(size_t)(b*TT + tt)*VV + wave*16 + ml] = acc[mt][r] + bo;
    }
}

extern "C" void kernel_launch(void* const* d_in, const int* in_sizes, int n_in,
                              void* d_out, int out_size, void* d_ws, size_t ws_size,
                              hipStream_t stream)
{
  (void)in_sizes; (void)n_in; (void)out_size; (void)ws_size;
  const int*   x     = (const int*)d_in[0];
  const int*   tgt   = (const int*)d_in[1];
  const float* eps   = (const float*)d_in[2];
  const float* emb   = (const float*)d_in[3];
  const float* Wih_f = (const float*)d_in[4];
  const float* Whh_f = (const float*)d_in[5];
  const float* b_f   = (const float*)d_in[6];
  const float* Wih_b = (const float*)d_in[7];
  const float* Whh_b = (const float*)d_in[8];
  const float* b_b   = (const float*)d_in[9];
  const float* W_mu  = (const float*)d_in[10];
  const float* b_mu  = (const float*)d_in[11];
  const float* W_lv  = (const float*)d_in[12];
  const float* b_lv  = (const float*)d_in[13];
  const float* W_di  = (const float*)d_in[14];
  const float* b_di  = (const float*)d_in[15];
  const float* Wih_d = (const float*)d_in[16];
  const float* Whh_d = (const float*)d_in[17];
  const float* b_d   = (const float*)d_in[18];
  const float* W_out = (const float*)d_in[19];
  const float* b_out = (const float*)d_in[20];

  char* ws = (char*)d_ws;
  u16* encW  = (u16*)(ws + OFF_ENCW);
  u16* decW  = (u16*)(ws + OFF_DECW);
  u16* woutW = (u16*)(ws + OFF_WOUT);
  u16* embB  = (u16*)(ws + OFF_EMBB);
  u16* henc  = (u16*)(ws + OFF_HENC);
  u16* hdec  = (u16*)(ws + OFF_HDEC);
  u16* zbf   = (u16*)(ws + OFF_ZBF);
  u16* hsbuf = (u16*)(ws + OFF_HS);
  unsigned* flg = (unsigned*)(ws + OFF_FLG);
  float* outp = (float*)d_out;

  prep_weights<<<2048, 256, 0, stream>>>(Wih_f, Whh_f, Wih_b, Whh_b, Wih_d, Whh_d, W_out, emb,
                                         encW, decW, woutW, embB);
  prep_zero<<<256, 256, 0, stream>>>((int4*)henc, flg);
  encoder_kernel<<<256, 256, 0, stream>>>(x, embB, b_f, b_b, encW, henc, flg);
  latent_kernel<<<32, 256, 0, stream>>>(eps, W_mu, b_mu, W_lv, b_lv, W_di, b_di,
                                        henc, hdec, zbf, outp);
  decoder_kernel<<<256, 256, 0, stream>>>(tgt, embB, b_d, decW, zbf, hdec, hsbuf, flg + 16*64);
  recon_kernel<<<1024, 256, 0, stream>>>(hsbuf, woutW, b_out, outp);
}